// Round 4
// baseline (32270.639 us; speedup 1.0000x reference)
//
#include <hip/hip_runtime.h>
#include <math.h>

#define NN 50000
#define NE 600000
#define HD 128
#define NL 10
#define LN_EPS 1e-5f
#define SCAN_B 256
#define NBLK ((NN + SCAN_B - 1) / SCAN_B)   // 196

typedef unsigned short ushort_t;

__device__ __forceinline__ float gelu_f(float x){
    return 0.5f * x * (1.0f + erff(x * 0.7071067811865475f));
}
__device__ __forceinline__ float bf2f(ushort_t u){
    unsigned int x = ((unsigned int)u) << 16;
    float f; __builtin_memcpy(&f, &x, 4); return f;
}
__device__ __forceinline__ ushort_t f2bf(float f){
    unsigned int x; __builtin_memcpy(&x, &f, 4);
    unsigned int lsb = (x >> 16) & 1u;
    x += 0x7fffu + lsb;                 // round-to-nearest-even
    return (ushort_t)(x >> 16);
}

// ---------------- sentinel fill (ws-too-small diagnostic) ----------------
__global__ void k_sentinel_out(float* __restrict__ out, int n, float v){
    int i = blockIdx.x*256 + threadIdx.x;
    if (i < n) out[i] = v;
}

// ---------------- encoder: h = gelu(LN(x @ W + b)) ----------------
__global__ __launch_bounds__(128) void k_encode_nodes(
    const float* __restrict__ x, const float* __restrict__ W,
    const float* __restrict__ b, const float* __restrict__ g,
    const float* __restrict__ beta, float* __restrict__ h)
{
    int n = blockIdx.x;
    int t = threadIdx.x;
    __shared__ float xs[7];
    __shared__ float red[4];
    if (t < 7) xs[t] = x[n*7 + t];
    __syncthreads();
    float acc = b[t];
    #pragma unroll
    for (int i = 0; i < 7; ++i) acc += xs[i] * W[i*HD + t];
    float s = acc, s2 = acc*acc;
    #pragma unroll
    for (int m = 32; m >= 1; m >>= 1) { s += __shfl_xor(s, m); s2 += __shfl_xor(s2, m); }
    int wave = t >> 6;
    if ((t & 63) == 0) { red[wave*2] = s; red[wave*2+1] = s2; }
    __syncthreads();
    s = red[0] + red[2]; s2 = red[1] + red[3];
    float mean = s * (1.0f/HD);
    float var  = s2 * (1.0f/HD) - mean*mean;
    float rs = rsqrtf(var + LN_EPS);
    float v = (acc - mean) * rs * g[t] + beta[t];
    h[(size_t)n*HD + t] = gelu_f(v);
}

// ---------------- edge encoder: ea = attr @ W + b (bf16 store) ----------------
__global__ __launch_bounds__(256) void k_encode_edges(
    const float* __restrict__ attr, const float* __restrict__ W,
    const float* __restrict__ b, ushort_t* __restrict__ ea)
{
    int e = blockIdx.x * 2 + (threadIdx.x >> 7);
    int c = threadIdx.x & 127;
    float acc = b[c];
    #pragma unroll
    for (int i = 0; i < 8; ++i) acc += attr[(size_t)e*8 + i] * W[i*HD + c];
    ea[(size_t)e*HD + c] = f2bf(acc);
}

// ---------------- CSR build (col is constant across layers) ----------------
__global__ void k_hist(const int* __restrict__ col, int* __restrict__ cnt){
    int e = blockIdx.x*256 + threadIdx.x;
    if (e < NE) atomicAdd(&cnt[col[e]], 1);
}

__global__ __launch_bounds__(256) void k_scan1(const int* __restrict__ cnt, int* __restrict__ bsum){
    __shared__ int s[256];
    int i = blockIdx.x*256 + threadIdx.x;
    int t = threadIdx.x;
    s[t] = (i < NN) ? cnt[i] : 0;
    __syncthreads();
    for (int off = 128; off >= 1; off >>= 1){
        if (t < off) s[t] += s[t+off];
        __syncthreads();
    }
    if (t == 0) bsum[blockIdx.x] = s[0];
}

__global__ __launch_bounds__(256) void k_scan2(const int* __restrict__ bsum, int* __restrict__ boff){
    __shared__ int s[256];
    int t = threadIdx.x;
    int v = (t < NBLK) ? bsum[t] : 0;
    s[t] = v; __syncthreads();
    for (int off = 1; off < 256; off <<= 1){
        int tmp = (t >= off) ? s[t-off] : 0;
        __syncthreads();
        s[t] += tmp;
        __syncthreads();
    }
    if (t < NBLK) boff[t] = s[t] - v;   // exclusive
}

__global__ __launch_bounds__(256) void k_scan3(const int* __restrict__ cnt, const int* __restrict__ boff,
        int* __restrict__ rowStart, float* __restrict__ invcnt){
    __shared__ int s[256];
    int i = blockIdx.x*256 + threadIdx.x;
    int t = threadIdx.x;
    int v = (i < NN) ? cnt[i] : 0;
    s[t] = v; __syncthreads();
    for (int off = 1; off < 256; off <<= 1){
        int tmp = (t >= off) ? s[t-off] : 0;
        __syncthreads();
        s[t] += tmp;
        __syncthreads();
    }
    if (i < NN){
        rowStart[i] = boff[blockIdx.x] + s[t] - v;
        invcnt[i]   = 1.0f / fmaxf((float)v, 1.0f);
    }
}

__global__ void k_fill(const int* __restrict__ col, const int* __restrict__ rowStart,
                       int* __restrict__ fill, int* __restrict__ edgeIds){
    int e = blockIdx.x*256 + threadIdx.x;
    if (e < NE){
        int c = col[e];
        int p = rowStart[c] + atomicAdd(&fill[c], 1);
        edgeIds[p] = e;
    }
}

// ---------------- fused edge update ----------------
// per block: 32 edges. A=[h[row]|h[col]|ea] (32x384) -> @W1(384x256)+b1 -> LN -> GELU
//           -> @W2(256x128)+b2 -> LN -> ea += .  (ea stored bf16)
// LDS: As 48K + Bs 12K + 256B = 60.3KB
__global__ __launch_bounds__(256) void k_edge_update(
    const float* __restrict__ h, ushort_t* __restrict__ ea,
    const int* __restrict__ row, const int* __restrict__ col,
    const float* __restrict__ W1, const float* __restrict__ b1,
    const float* __restrict__ g1, const float* __restrict__ bt1,
    const float* __restrict__ W2, const float* __restrict__ b2,
    const float* __restrict__ g2, const float* __restrict__ bt2)
{
    __shared__ float As[32][384];   // aliased as Ts[32][256] after phase 1
    __shared__ float Bs[12*256];    // phase1 [12][256], phase2 [16][128]
    __shared__ int ridx[32], cidx[32];

    const int tid = threadIdx.x;
    const int tx = tid & 31;        // col group
    const int ty = tid >> 5;        // edge group (0..7), 4 edges each
    const int eBase = blockIdx.x * 32;

    if (tid < 32){ ridx[tid] = row[eBase+tid]; cidx[tid] = col[eBase+tid]; }
    __syncthreads();

    // gather h[row], h[col]: 32 edges x 2 segs x 32 float4 = 2048 slots
    #pragma unroll
    for (int it = 0; it < 8; ++it){
        int f = tid + it*256;
        int e = f >> 6;
        int r = f & 63;
        int seg = r >> 5;
        int q = r & 31;
        const float* src = (seg == 0) ? (h + (size_t)ridx[e]*HD) : (h + (size_t)cidx[e]*HD);
        *(float4*)&As[e][seg*128 + q*4] = *(const float4*)(src + q*4);
    }
    // gather ea (bf16): 32 edges x 16 uint4 (8 ch each) = 512 slots
    #pragma unroll
    for (int it = 0; it < 2; ++it){
        int f = tid + it*256;
        int e = f >> 4;
        int q = f & 15;
        uint4 v = *(const uint4*)(ea + (size_t)(eBase+e)*HD + q*8);
        unsigned int ws[4] = {v.x, v.y, v.z, v.w};
        #pragma unroll
        for (int w = 0; w < 4; ++w){
            unsigned int lo = ws[w] << 16;
            unsigned int hi = ws[w] & 0xffff0000u;
            float flo, fhi;
            __builtin_memcpy(&flo, &lo, 4);
            __builtin_memcpy(&fhi, &hi, 4);
            As[e][256 + q*8 + 2*w]     = flo;
            As[e][256 + q*8 + 2*w + 1] = fhi;
        }
    }
    __syncthreads();

    // ---- phase 1: (32x384)@(384x256), K-chunks of 12 ----
    float acc[4][8];
    #pragma unroll
    for (int i=0;i<4;++i)
        #pragma unroll
        for (int j=0;j<8;++j) acc[i][j] = 0.f;

    for (int k0 = 0; k0 < 384; k0 += 12){
        #pragma unroll
        for (int it = 0; it < 3; ++it){
            int f = tid + it*256;          // 12 rows x 64 float4
            int kk = f >> 6;
            int q  = f & 63;
            *(float4*)&Bs[kk*256 + q*4] = *(const float4*)(W1 + (size_t)(k0+kk)*256 + q*4);
        }
        __syncthreads();
        #pragma unroll
        for (int kk = 0; kk < 12; ++kk){
            float a0 = As[ty*4+0][k0+kk];
            float a1 = As[ty*4+1][k0+kk];
            float a2 = As[ty*4+2][k0+kk];
            float a3 = As[ty*4+3][k0+kk];
            float4 bl = *(float4*)&Bs[kk*256 + tx*8];
            float4 bh = *(float4*)&Bs[kk*256 + tx*8+4];
            float bv[8] = {bl.x,bl.y,bl.z,bl.w,bh.x,bh.y,bh.z,bh.w};
            #pragma unroll
            for (int j=0;j<8;++j){
                acc[0][j] += a0*bv[j];
                acc[1][j] += a1*bv[j];
                acc[2][j] += a2*bv[j];
                acc[3][j] += a3*bv[j];
            }
        }
        __syncthreads();
    }

    // ---- epilogue 1: +b1, LN(256), GELU -> Ts ----
    float* Ts = &As[0][0];   // [32][256]
    const int c0 = tx*8;
    #pragma unroll
    for (int i=0;i<4;++i){
        float v[8]; float es=0.f, es2=0.f;
        #pragma unroll
        for (int j=0;j<8;++j){
            float tv = acc[i][j] + b1[c0+j];
            v[j]=tv; es+=tv; es2+=tv*tv;
        }
        #pragma unroll
        for (int m=1;m<32;m<<=1){ es += __shfl_xor(es,m); es2 += __shfl_xor(es2,m); }
        float mean = es*(1.f/256.f);
        float var  = es2*(1.f/256.f) - mean*mean;
        float rs = rsqrtf(var + LN_EPS);
        #pragma unroll
        for (int j=0;j<8;++j){
            float tv = (v[j]-mean)*rs*g1[c0+j] + bt1[c0+j];
            v[j] = gelu_f(tv);
        }
        *(float4*)&Ts[(ty*4+i)*256 + c0]     = make_float4(v[0],v[1],v[2],v[3]);
        *(float4*)&Ts[(ty*4+i)*256 + c0 + 4] = make_float4(v[4],v[5],v[6],v[7]);
    }
    __syncthreads();

    // ---- phase 2: (32x256)@(256x128), K-chunks of 16 ----
    float acc2[4][4];
    #pragma unroll
    for (int i=0;i<4;++i)
        #pragma unroll
        for (int j=0;j<4;++j) acc2[i][j] = 0.f;
    const int c2 = tx*4;

    for (int k0 = 0; k0 < 256; k0 += 16){
        #pragma unroll
        for (int it = 0; it < 2; ++it){
            int f = tid + it*256;          // 16 rows x 32 float4
            int kk = f >> 5;
            int q  = f & 31;
            *(float4*)&Bs[kk*128 + q*4] = *(const float4*)(W2 + (size_t)(k0+kk)*128 + q*4);
        }
        __syncthreads();
        #pragma unroll
        for (int kk = 0; kk < 16; ++kk){
            float a0 = Ts[(ty*4+0)*256 + k0+kk];
            float a1 = Ts[(ty*4+1)*256 + k0+kk];
            float a2 = Ts[(ty*4+2)*256 + k0+kk];
            float a3 = Ts[(ty*4+3)*256 + k0+kk];
            float4 b4 = *(float4*)&Bs[kk*128 + c2];
            float bv[4] = {b4.x,b4.y,b4.z,b4.w};
            #pragma unroll
            for (int j=0;j<4;++j){
                acc2[0][j] += a0*bv[j];
                acc2[1][j] += a1*bv[j];
                acc2[2][j] += a2*bv[j];
                acc2[3][j] += a3*bv[j];
            }
        }
        __syncthreads();
    }

    // ---- epilogue 2: +b2, LN(128), residual (bf16 read-modify-write) ----
    #pragma unroll
    for (int i=0;i<4;++i){
        int ge = eBase + ty*4 + i;
        float v[4]; float es=0.f, es2=0.f;
        #pragma unroll
        for (int j=0;j<4;++j){
            float tv = acc2[i][j] + b2[c2+j];
            v[j]=tv; es+=tv; es2+=tv*tv;
        }
        #pragma unroll
        for (int m=1;m<32;m<<=1){ es += __shfl_xor(es,m); es2 += __shfl_xor(es2,m); }
        float mean = es*(1.f/128.f);
        float var  = es2*(1.f/128.f) - mean*mean;
        float rs = rsqrtf(var + LN_EPS);
        ushort4 oldv = *(const ushort4*)(ea + (size_t)ge*HD + c2);
        ushort4 outv;
        outv.x = f2bf(bf2f(oldv.x) + (v[0]-mean)*rs*g2[c2+0] + bt2[c2+0]);
        outv.y = f2bf(bf2f(oldv.y) + (v[1]-mean)*rs*g2[c2+1] + bt2[c2+1]);
        outv.z = f2bf(bf2f(oldv.z) + (v[2]-mean)*rs*g2[c2+2] + bt2[c2+2]);
        outv.w = f2bf(bf2f(oldv.w) + (v[3]-mean)*rs*g2[c2+3] + bt2[c2+3]);
        *(ushort4*)(ea + (size_t)ge*HD + c2) = outv;
    }
}

// ---------------- fused node update (aggregation fused in) ----------------
__global__ __launch_bounds__(256) void k_node_update(
    float* __restrict__ h, const ushort_t* __restrict__ ea,
    const int* __restrict__ rowSt, const int* __restrict__ cnt,
    const float* __restrict__ invcnt, const int* __restrict__ edgeIds,
    const float* __restrict__ W1, const float* __restrict__ b1,
    const float* __restrict__ g1, const float* __restrict__ bt1,
    const float* __restrict__ W2, const float* __restrict__ b2,
    const float* __restrict__ g2, const float* __restrict__ bt2)
{
    __shared__ float As[32][256];   // [h | agg]; aliased as Ts after phase 1
    __shared__ float Bs[16][256];

    const int tid = threadIdx.x;
    const int tx = tid & 31;
    const int ty = tid >> 5;
    const int nBase = blockIdx.x * 32;

    // h part: 32 nodes x 32 float4
    #pragma unroll
    for (int it = 0; it < 4; ++it){
        int f = tid + it*256;
        int n = f >> 5;
        int q = f & 31;
        int gn = nBase + n;
        float4 v = make_float4(0.f,0.f,0.f,0.f);
        if (gn < NN) v = *(const float4*)(h + (size_t)gn*HD + q*4);
        *(float4*)&As[n][q*4] = v;
    }
    // agg part: CSR gather-mean, 2 groups of 128 threads x 16 nodes each
    {
        const int cg  = tid & 127;
        const int grp = tid >> 7;
        for (int i = 0; i < 16; ++i){
            int ln = grp*16 + i;
            int gn = nBase + ln;
            float s = 0.f;
            if (gn < NN){
                int st = rowSt[gn], dg = cnt[gn];
                for (int j = 0; j < dg; ++j){
                    int e = edgeIds[st + j];
                    s += bf2f(ea[(size_t)e*HD + cg]);
                }
                s *= invcnt[gn];
            }
            As[ln][128 + cg] = s;
        }
    }
    __syncthreads();

    // ---- phase 1: (32x256)@(256x256) ----
    float acc[4][8];
    #pragma unroll
    for (int i=0;i<4;++i)
        #pragma unroll
        for (int j=0;j<8;++j) acc[i][j] = 0.f;

    for (int k0 = 0; k0 < 256; k0 += 16){
        #pragma unroll
        for (int it = 0; it < 4; ++it){
            int f = tid + it*256;
            int kk = f >> 6;
            int q  = f & 63;
            *(float4*)&Bs[kk][q*4] = *(const float4*)(W1 + (size_t)(k0+kk)*256 + q*4);
        }
        __syncthreads();
        #pragma unroll
        for (int kk = 0; kk < 16; ++kk){
            float a0 = As[ty*4+0][k0+kk];
            float a1 = As[ty*4+1][k0+kk];
            float a2 = As[ty*4+2][k0+kk];
            float a3 = As[ty*4+3][k0+kk];
            float4 bl = *(float4*)&Bs[kk][tx*8];
            float4 bh = *(float4*)&Bs[kk][tx*8+4];
            float bv[8] = {bl.x,bl.y,bl.z,bl.w,bh.x,bh.y,bh.z,bh.w};
            #pragma unroll
            for (int j=0;j<8;++j){
                acc[0][j] += a0*bv[j];
                acc[1][j] += a1*bv[j];
                acc[2][j] += a2*bv[j];
                acc[3][j] += a3*bv[j];
            }
        }
        __syncthreads();
    }

    float* Ts = &As[0][0];
    const int c0 = tx*8;
    #pragma unroll
    for (int i=0;i<4;++i){
        float v[8]; float es=0.f, es2=0.f;
        #pragma unroll
        for (int j=0;j<8;++j){
            float tv = acc[i][j] + b1[c0+j];
            v[j]=tv; es+=tv; es2+=tv*tv;
        }
        #pragma unroll
        for (int m=1;m<32;m<<=1){ es += __shfl_xor(es,m); es2 += __shfl_xor(es2,m); }
        float mean = es*(1.f/256.f);
        float var  = es2*(1.f/256.f) - mean*mean;
        float rs = rsqrtf(var + LN_EPS);
        #pragma unroll
        for (int j=0;j<8;++j){
            float tv = (v[j]-mean)*rs*g1[c0+j] + bt1[c0+j];
            v[j] = gelu_f(tv);
        }
        *(float4*)&Ts[(ty*4+i)*256 + c0]     = make_float4(v[0],v[1],v[2],v[3]);
        *(float4*)&Ts[(ty*4+i)*256 + c0 + 4] = make_float4(v[4],v[5],v[6],v[7]);
    }
    __syncthreads();

    // ---- phase 2: (32x256)@(256x128) ----
    float acc2[4][4];
    #pragma unroll
    for (int i=0;i<4;++i)
        #pragma unroll
        for (int j=0;j<4;++j) acc2[i][j] = 0.f;
    const int c2 = tx*4;

    for (int k0 = 0; k0 < 256; k0 += 16){
        #pragma unroll
        for (int it = 0; it < 2; ++it){
            int f = tid + it*256;
            int kk = f >> 5;
            int q  = f & 31;
            *(float4*)&Bs[0][kk*128 + q*4] = *(const float4*)(W2 + (size_t)(k0+kk)*128 + q*4);
        }
        __syncthreads();
        #pragma unroll
        for (int kk = 0; kk < 16; ++kk){
            float a0 = Ts[(ty*4+0)*256 + k0+kk];
            float a1 = Ts[(ty*4+1)*256 + k0+kk];
            float a2 = Ts[(ty*4+2)*256 + k0+kk];
            float a3 = Ts[(ty*4+3)*256 + k0+kk];
            float4 b4 = *(float4*)&Bs[0][kk*128 + c2];
            float bv[4] = {b4.x,b4.y,b4.z,b4.w};
            #pragma unroll
            for (int j=0;j<4;++j){
                acc2[0][j] += a0*bv[j];
                acc2[1][j] += a1*bv[j];
                acc2[2][j] += a2*bv[j];
                acc2[3][j] += a3*bv[j];
            }
        }
        __syncthreads();
    }

    #pragma unroll
    for (int i=0;i<4;++i){
        int gn = nBase + ty*4 + i;
        float v[4]; float es=0.f, es2=0.f;
        #pragma unroll
        for (int j=0;j<4;++j){
            float tv = acc2[i][j] + b2[c2+j];
            v[j]=tv; es+=tv; es2+=tv*tv;
        }
        #pragma unroll
        for (int m=1;m<32;m<<=1){ es += __shfl_xor(es,m); es2 += __shfl_xor(es2,m); }
        float mean = es*(1.f/128.f);
        float var  = es2*(1.f/128.f) - mean*mean;
        float rs = rsqrtf(var + LN_EPS);
        if (gn < NN){
            float4 oldv = *(const float4*)(h + (size_t)gn*HD + c2);
            float4 outv;
            outv.x = oldv.x + (v[0]-mean)*rs*g2[c2+0] + bt2[c2+0];
            outv.y = oldv.y + (v[1]-mean)*rs*g2[c2+1] + bt2[c2+1];
            outv.z = oldv.z + (v[2]-mean)*rs*g2[c2+2] + bt2[c2+2];
            outv.w = oldv.w + (v[3]-mean)*rs*g2[c2+3] + bt2[c2+3];
            *(float4*)(h + (size_t)gn*HD + c2) = outv;
        }
    }
}

// ---------------- decoder ----------------
__global__ __launch_bounds__(128) void k_decode(
    const float* __restrict__ h, const float* __restrict__ W1,
    const float* __restrict__ b1, const float* __restrict__ W2,
    const float* __restrict__ b2, float* __restrict__ out)
{
    int n = blockIdx.x, t = threadIdx.x;
    __shared__ float hs[128];
    __shared__ float red[8];
    hs[t] = h[(size_t)n*HD + t];
    __syncthreads();
    float o = b1[t];
    #pragma unroll 8
    for (int k = 0; k < 128; ++k) o += hs[k] * W1[k*128 + t];
    o = gelu_f(o);
    float p0 = o*W2[t*4+0], p1 = o*W2[t*4+1], p2 = o*W2[t*4+2], p3 = o*W2[t*4+3];
    #pragma unroll
    for (int m = 32; m >= 1; m >>= 1){
        p0 += __shfl_xor(p0, m); p1 += __shfl_xor(p1, m);
        p2 += __shfl_xor(p2, m); p3 += __shfl_xor(p3, m);
    }
    int wave = t >> 6;
    if ((t & 63) == 0){ red[wave*4+0]=p0; red[wave*4+1]=p1; red[wave*4+2]=p2; red[wave*4+3]=p3; }
    __syncthreads();
    if (t < 4) out[(size_t)n*4 + t] = red[t] + red[4+t] + b2[t];
}

// ---------------- launch ----------------
extern "C" void kernel_launch(void* const* d_in, const int* in_sizes, int n_in,
                              void* d_out, int out_size, void* d_ws, size_t ws_size,
                              hipStream_t stream)
{
    const float* x      = (const float*)d_in[0];
    const int*   eidx   = (const int*)d_in[1];
    const float* eattr  = (const float*)d_in[2];
    const float* enc_W  = (const float*)d_in[3];
    const float* enc_b  = (const float*)d_in[4];
    const float* enc_g  = (const float*)d_in[5];
    const float* enc_bt = (const float*)d_in[6];
    const float* ee_W   = (const float*)d_in[7];
    const float* ee_b   = (const float*)d_in[8];
    const float* eW1    = (const float*)d_in[9];
    const float* eb1    = (const float*)d_in[10];
    const float* eg1    = (const float*)d_in[11];
    const float* ebt1   = (const float*)d_in[12];
    const float* eW2    = (const float*)d_in[13];
    const float* eb2    = (const float*)d_in[14];
    const float* eg2    = (const float*)d_in[15];
    const float* ebt2   = (const float*)d_in[16];
    const float* nW1    = (const float*)d_in[17];
    const float* nb1    = (const float*)d_in[18];
    const float* ng1    = (const float*)d_in[19];
    const float* nbt1   = (const float*)d_in[20];
    const float* nW2    = (const float*)d_in[21];
    const float* nb2    = (const float*)d_in[22];
    const float* ng2    = (const float*)d_in[23];
    const float* nbt2   = (const float*)d_in[24];
    const float* dec_W1 = (const float*)d_in[25];
    const float* dec_b1 = (const float*)d_in[26];
    const float* dec_W2 = (const float*)d_in[27];
    const float* dec_b2 = (const float*)d_in[28];

    const int* row = eidx;
    const int* col = eidx + NE;

    char* ws0 = (char*)d_ws;
    char* ws = ws0;
    auto alloc = [&](size_t bytes) -> char* {
        char* p = ws;
        ws += (bytes + 255) & ~(size_t)255;
        return p;
    };
    ushort_t* ea      = (ushort_t*)alloc((size_t)NE*HD*2);   // 153.6 MB bf16
    float*    h       = (float*)   alloc((size_t)NN*HD*4);   // 25.6 MB
    int*      cnt     = (int*)     alloc((size_t)NN*4);
    int*      rowSt   = (int*)     alloc((size_t)NN*4);
    int*      fill    = (int*)     alloc((size_t)NN*4);
    float*    invcnt  = (float*)   alloc((size_t)NN*4);
    int*      edgeIds = (int*)     alloc((size_t)NE*4);
    int*      bsum    = (int*)     alloc(256*4);
    int*      boff    = (int*)     alloc(256*4);

    size_t need = (size_t)(ws - ws0);
    if (ws_size < need){
        // sentinel 3.0: distinguishes "ws too small" from "nothing ran" (zeros)
        k_sentinel_out<<<(out_size+255)/256, 256, 0, stream>>>((float*)d_out, out_size, 3.0f);
        return;
    }

    hipMemsetAsync(cnt,  0, (size_t)NN*4, stream);
    hipMemsetAsync(fill, 0, (size_t)NN*4, stream);

    k_encode_nodes<<<NN, 128, 0, stream>>>(x, enc_W, enc_b, enc_g, enc_bt, h);
    k_encode_edges<<<NE/2, 256, 0, stream>>>(eattr, ee_W, ee_b, ea);

    k_hist <<<(NE+255)/256, 256, 0, stream>>>(col, cnt);
    k_scan1<<<NBLK, 256, 0, stream>>>(cnt, bsum);
    k_scan2<<<1, 256, 0, stream>>>(bsum, boff);
    k_scan3<<<NBLK, 256, 0, stream>>>(cnt, boff, rowSt, invcnt);
    k_fill <<<(NE+255)/256, 256, 0, stream>>>(col, rowSt, fill, edgeIds);

    for (int l = 0; l < NL; ++l){
        k_edge_update<<<NE/32, 256, 0, stream>>>(h, ea, row, col,
            eW1 + (size_t)l*384*256, eb1 + l*256, eg1 + l*256, ebt1 + l*256,
            eW2 + (size_t)l*256*128, eb2 + l*128, eg2 + l*128, ebt2 + l*128);
        k_node_update<<<(NN+31)/32, 256, 0, stream>>>(h, ea, rowSt, cnt, invcnt, edgeIds,
            nW1 + (size_t)l*256*256, nb1 + l*256, ng1 + l*256, nbt1 + l*256,
            nW2 + (size_t)l*256*128, nb2 + l*128, ng2 + l*128, nbt2 + l*128);
    }

    k_decode<<<NN, 128, 0, stream>>>(h, dec_W1, dec_b1, dec_W2, dec_b2, (float*)d_out);
}

// Round 6
// 13111.310 us; speedup vs baseline: 2.4613x; 2.4613x over previous
//
#include <hip/hip_runtime.h>
#include <math.h>

#define NN 50000
#define NE 600000
#define HD 128
#define NL 10
#define LN_EPS 1e-5f
#define SCAN_B 256
#define NBLK ((NN + SCAN_B - 1) / SCAN_B)   // 196

typedef unsigned short ushort_t;
typedef __attribute__((ext_vector_type(8))) short bf16x8;
typedef __attribute__((ext_vector_type(4))) float f32x4;

__device__ __forceinline__ float gelu_f(float x){
    return 0.5f * x * (1.0f + erff(x * 0.7071067811865475f));
}
__device__ __forceinline__ float bf2f(ushort_t u){
    unsigned int x = ((unsigned int)u) << 16;
    float f; __builtin_memcpy(&f, &x, 4); return f;
}
__device__ __forceinline__ ushort_t f2bf(float f){
    unsigned int x; __builtin_memcpy(&x, &f, 4);
    unsigned int lsb = (x >> 16) & 1u;
    x += 0x7fffu + lsb;                 // round-to-nearest-even
    return (ushort_t)(x >> 16);
}

// ---------------- sentinel fill (ws-too-small diagnostic) ----------------
__global__ void k_sentinel_out(float* __restrict__ out, int n, float v){
    int i = blockIdx.x*256 + threadIdx.x;
    if (i < n) out[i] = v;
}

// ---------------- weight pre-transpose+convert: W1T[l][n][k] = bf16(W1[l][k][n]) ----------------
__global__ void k_w1t(const float* __restrict__ W, ushort_t* __restrict__ WT){
    int idx = blockIdx.x*256 + threadIdx.x;           // over NL*256*384
    if (idx >= NL*256*384) return;
    int l = idx / (256*384);
    int rem = idx - l*(256*384);
    int n = rem / 384;
    int k = rem - n*384;
    WT[idx] = f2bf(W[(size_t)l*384*256 + (size_t)k*256 + n]);
}
__global__ void k_w2t(const float* __restrict__ W, ushort_t* __restrict__ WT){
    int idx = blockIdx.x*256 + threadIdx.x;           // over NL*128*256
    if (idx >= NL*128*256) return;
    int l = idx / (128*256);
    int rem = idx - l*(128*256);
    int n = rem / 256;
    int k = rem - n*256;
    WT[idx] = f2bf(W[(size_t)l*256*128 + (size_t)k*128 + n]);
}

// ---------------- encoder: h = gelu(LN(x @ W + b)) ----------------
__global__ __launch_bounds__(128) void k_encode_nodes(
    const float* __restrict__ x, const float* __restrict__ W,
    const float* __restrict__ b, const float* __restrict__ g,
    const float* __restrict__ beta, float* __restrict__ h)
{
    int n = blockIdx.x;
    int t = threadIdx.x;
    __shared__ float xs[7];
    __shared__ float red[4];
    if (t < 7) xs[t] = x[n*7 + t];
    __syncthreads();
    float acc = b[t];
    #pragma unroll
    for (int i = 0; i < 7; ++i) acc += xs[i] * W[i*HD + t];
    float s = acc, s2 = acc*acc;
    #pragma unroll
    for (int m = 32; m >= 1; m >>= 1) { s += __shfl_xor(s, m); s2 += __shfl_xor(s2, m); }
    int wave = t >> 6;
    if ((t & 63) == 0) { red[wave*2] = s; red[wave*2+1] = s2; }
    __syncthreads();
    s = red[0] + red[2]; s2 = red[1] + red[3];
    float mean = s * (1.0f/HD);
    float var  = s2 * (1.0f/HD) - mean*mean;
    float rs = rsqrtf(var + LN_EPS);
    float v = (acc - mean) * rs * g[t] + beta[t];
    h[(size_t)n*HD + t] = gelu_f(v);
}

// ---------------- edge encoder: ea = attr @ W + b (bf16 store) ----------------
__global__ __launch_bounds__(256) void k_encode_edges(
    const float* __restrict__ attr, const float* __restrict__ W,
    const float* __restrict__ b, ushort_t* __restrict__ ea)
{
    int e = blockIdx.x * 2 + (threadIdx.x >> 7);
    int c = threadIdx.x & 127;
    float acc = b[c];
    #pragma unroll
    for (int i = 0; i < 8; ++i) acc += attr[(size_t)e*8 + i] * W[i*HD + c];
    ea[(size_t)e*HD + c] = f2bf(acc);
}

// ---------------- CSR build ----------------
__global__ void k_hist(const int* __restrict__ col, int* __restrict__ cnt){
    int e = blockIdx.x*256 + threadIdx.x;
    if (e < NE) atomicAdd(&cnt[col[e]], 1);
}

__global__ __launch_bounds__(256) void k_scan1(const int* __restrict__ cnt, int* __restrict__ bsum){
    __shared__ int s[256];
    int i = blockIdx.x*256 + threadIdx.x;
    int t = threadIdx.x;
    s[t] = (i < NN) ? cnt[i] : 0;
    __syncthreads();
    for (int off = 128; off >= 1; off >>= 1){
        if (t < off) s[t] += s[t+off];
        __syncthreads();
    }
    if (t == 0) bsum[blockIdx.x] = s[0];
}

__global__ __launch_bounds__(256) void k_scan2(const int* __restrict__ bsum, int* __restrict__ boff){
    __shared__ int s[256];
    int t = threadIdx.x;
    int v = (t < NBLK) ? bsum[t] : 0;
    s[t] = v; __syncthreads();
    for (int off = 1; off < 256; off <<= 1){
        int tmp = (t >= off) ? s[t-off] : 0;
        __syncthreads();
        s[t] += tmp;
        __syncthreads();
    }
    if (t < NBLK) boff[t] = s[t] - v;   // exclusive
}

__global__ __launch_bounds__(256) void k_scan3(const int* __restrict__ cnt, const int* __restrict__ boff,
        int* __restrict__ rowStart, float* __restrict__ invcnt){
    __shared__ int s[256];
    int i = blockIdx.x*256 + threadIdx.x;
    int t = threadIdx.x;
    int v = (i < NN) ? cnt[i] : 0;
    s[t] = v; __syncthreads();
    for (int off = 1; off < 256; off <<= 1){
        int tmp = (t >= off) ? s[t-off] : 0;
        __syncthreads();
        s[t] += tmp;
        __syncthreads();
    }
    if (i < NN){
        rowStart[i] = boff[blockIdx.x] + s[t] - v;
        invcnt[i]   = 1.0f / fmaxf((float)v, 1.0f);
    }
}

__global__ void k_fill(const int* __restrict__ col, const int* __restrict__ rowStart,
                       int* __restrict__ fill, int* __restrict__ edgeIds){
    int e = blockIdx.x*256 + threadIdx.x;
    if (e < NE){
        int c = col[e];
        int p = rowStart[c] + atomicAdd(&fill[c], 1);
        edgeIds[p] = e;
    }
}

// ---------------- MFMA fused edge update ----------------
// 32 edges/block, 4 waves. A=[h[row]|h[col]|ea] 32x384 bf16 in LDS.
// GEMM1 via mfma_f32_16x16x32_bf16 against W1T (bf16, [256][384], L2-cached),
// LN+GELU in-register (cross-wave reduce via 1KB LDS), GEMM2 vs W2T [128][256],
// LN + residual into ea (bf16).
// Fragment maps: A: row=lane&15, k=(lane>>4)*8+j.  B: col=lane&15, k=(lane>>4)*8+j.
// C/D: col=lane&15, row=(lane>>4)*4+reg (HW-verified).
#define AP 392   // A LDS row stride (shorts): 784B, 16B-aligned, rows spread 4 banks
#define A2P 264  // A2 row stride (shorts): 528B, 16B-aligned, rows spread 4 banks
__global__ __launch_bounds__(256) void k_edge_update(
    const float* __restrict__ h, ushort_t* __restrict__ ea,
    const int* __restrict__ row, const int* __restrict__ col,
    const ushort_t* __restrict__ W1T, const float* __restrict__ b1,
    const float* __restrict__ g1, const float* __restrict__ bt1,
    const ushort_t* __restrict__ W2T, const float* __restrict__ b2,
    const float* __restrict__ g2, const float* __restrict__ bt2)
{
    __shared__ short As[32*AP];          // 25088 B; aliased as A2s[32][A2P] after phase 1
    __shared__ float red[4][32][2];      // 1 KB cross-wave LN partials
    __shared__ int ridx[32], cidx[32];

    const int tid  = threadIdx.x;
    const int lane = tid & 63;
    const int w    = tid >> 6;           // wave 0..3
    const int l15  = lane & 15;
    const int lg   = lane >> 4;          // 0..3
    const int eBase = blockIdx.x * 32;

    if (tid < 32){ ridx[tid] = row[eBase+tid]; cidx[tid] = col[eBase+tid]; }
    __syncthreads();

    // ---- stage A tile (bf16) ----
    // seg0/seg1: h[ridx]/h[cidx]: 32 edges x 32 float4 each
    #pragma unroll
    for (int it = 0; it < 4; ++it){
        int f = tid + it*256;            // 0..1023
        int e = f >> 5, q = f & 31;
        float4 v = *(const float4*)(h + (size_t)ridx[e]*HD + q*4);
        *(ushort4*)&As[e*AP + q*4] = make_ushort4(f2bf(v.x), f2bf(v.y), f2bf(v.z), f2bf(v.w));
    }
    #pragma unroll
    for (int it = 0; it < 4; ++it){
        int f = tid + it*256;
        int e = f >> 5, q = f & 31;
        float4 v = *(const float4*)(h + (size_t)cidx[e]*HD + q*4);
        *(ushort4*)&As[e*AP + 128 + q*4] = make_ushort4(f2bf(v.x), f2bf(v.y), f2bf(v.z), f2bf(v.w));
    }
    // seg2: ea bf16 copy: 32 edges x 16 uint4
    #pragma unroll
    for (int it = 0; it < 2; ++it){
        int f = tid + it*256;            // 0..511
        int e = f >> 4, q = f & 15;
        uint4 v = *(const uint4*)(ea + (size_t)(eBase+e)*HD + q*8);
        *(uint4*)&As[e*AP + 256 + q*8] = v;
    }
    __syncthreads();

    // ---- phase 1: (32x384)@(384x256) via MFMA ----
    f32x4 acc[2][4];
    #pragma unroll
    for (int rt=0;rt<2;++rt)
        #pragma unroll
        for (int c=0;c<4;++c) acc[rt][c] = (f32x4){0.f,0.f,0.f,0.f};

    #pragma unroll 2
    for (int kc = 0; kc < 12; ++kc){
        int k0 = kc*32 + lg*8;
        bf16x8 a0 = *(const bf16x8*)&As[(l15     )*AP + k0];
        bf16x8 a1 = *(const bf16x8*)&As[(l15 + 16)*AP + k0];
        #pragma unroll
        for (int c=0;c<4;++c){
            int colg = w*64 + c*16 + l15;
            bf16x8 b = *(const bf16x8*)&W1T[(size_t)colg*384 + k0];
            acc[0][c] = __builtin_amdgcn_mfma_f32_16x16x32_bf16(a0, b, acc[0][c], 0, 0, 0);
            acc[1][c] = __builtin_amdgcn_mfma_f32_16x16x32_bf16(a1, b, acc[1][c], 0, 0, 0);
        }
    }

    // ---- epilogue 1: +b1, LN(256), GELU -> A2s (bf16) ----
    float b1c[4], g1c[4], t1c[4];
    #pragma unroll
    for (int c=0;c<4;++c){
        int colg = w*64 + c*16 + l15;
        b1c[c] = b1[colg]; g1c[c] = g1[colg]; t1c[c] = bt1[colg];
    }
    float xv[2][4][4];
    #pragma unroll
    for (int rt=0;rt<2;++rt)
        #pragma unroll
        for (int c=0;c<4;++c)
            #pragma unroll
            for (int i=0;i<4;++i) xv[rt][c][i] = acc[rt][c][i] + b1c[c];

    float rsum[2][4], rsq[2][4];
    #pragma unroll
    for (int rt=0;rt<2;++rt)
        #pragma unroll
        for (int i=0;i<4;++i){
            float s=0.f, q=0.f;
            #pragma unroll
            for (int c=0;c<4;++c){ float v=xv[rt][c][i]; s+=v; q+=v*v; }
            #pragma unroll
            for (int m=1;m<16;m<<=1){ s += __shfl_xor(s,m); q += __shfl_xor(q,m); }
            rsum[rt][i]=s; rsq[rt][i]=q;
        }
    if (l15 == 0){
        #pragma unroll
        for (int rt=0;rt<2;++rt)
            #pragma unroll
            for (int i=0;i<4;++i){
                int r = rt*16 + lg*4 + i;
                red[w][r][0] = rsum[rt][i];
                red[w][r][1] = rsq[rt][i];
            }
    }
    __syncthreads();   // also guarantees all phase-1 LDS reads done before A2s overwrite

    short* A2s = &As[0];
    #pragma unroll
    for (int rt=0;rt<2;++rt)
        #pragma unroll
        for (int i=0;i<4;++i){
            int r = rt*16 + lg*4 + i;
            float S = red[0][r][0]+red[1][r][0]+red[2][r][0]+red[3][r][0];
            float Q = red[0][r][1]+red[1][r][1]+red[2][r][1]+red[3][r][1];
            float mean = S * (1.f/256.f);
            float var  = Q * (1.f/256.f) - mean*mean;
            float rs = rsqrtf(var + LN_EPS);
            #pragma unroll
            for (int c=0;c<4;++c){
                int colg = w*64 + c*16 + l15;
                float v = (xv[rt][c][i]-mean)*rs*g1c[c] + t1c[c];
                A2s[r*A2P + colg] = (short)f2bf(gelu_f(v));
            }
        }
    __syncthreads();

    // ---- phase 2: (32x256)@(256x128) via MFMA ----
    f32x4 acc2[2][2];
    #pragma unroll
    for (int rt=0;rt<2;++rt)
        #pragma unroll
        for (int c=0;c<2;++c) acc2[rt][c] = (f32x4){0.f,0.f,0.f,0.f};

    #pragma unroll 2
    for (int kc = 0; kc < 8; ++kc){
        int k0 = kc*32 + lg*8;
        bf16x8 a0 = *(const bf16x8*)&A2s[(l15     )*A2P + k0];
        bf16x8 a1 = *(const bf16x8*)&A2s[(l15 + 16)*A2P + k0];
        #pragma unroll
        for (int c=0;c<2;++c){
            int colg = w*32 + c*16 + l15;
            bf16x8 b = *(const bf16x8*)&W2T[(size_t)colg*256 + k0];
            acc2[0][c] = __builtin_amdgcn_mfma_f32_16x16x32_bf16(a0, b, acc2[0][c], 0, 0, 0);
            acc2[1][c] = __builtin_amdgcn_mfma_f32_16x16x32_bf16(a1, b, acc2[1][c], 0, 0, 0);
        }
    }

    // ---- epilogue 2: +b2, LN(128), residual into ea (bf16) ----
    float b2c[2], g2c[2], t2c[2];
    #pragma unroll
    for (int c=0;c<2;++c){
        int colg = w*32 + c*16 + l15;
        b2c[c] = b2[colg]; g2c[c] = g2[colg]; t2c[c] = bt2[colg];
    }
    float yv[2][2][4];
    #pragma unroll
    for (int rt=0;rt<2;++rt)
        #pragma unroll
        for (int c=0;c<2;++c)
            #pragma unroll
            for (int i=0;i<4;++i) yv[rt][c][i] = acc2[rt][c][i] + b2c[c];

    float rsum2[2][4], rsq2[2][4];
    #pragma unroll
    for (int rt=0;rt<2;++rt)
        #pragma unroll
        for (int i=0;i<4;++i){
            float s=0.f, q=0.f;
            #pragma unroll
            for (int c=0;c<2;++c){ float v=yv[rt][c][i]; s+=v; q+=v*v; }
            #pragma unroll
            for (int m=1;m<16;m<<=1){ s += __shfl_xor(s,m); q += __shfl_xor(q,m); }
            rsum2[rt][i]=s; rsq2[rt][i]=q;
        }
    __syncthreads();   // ensure epi-1 red reads done before reuse
    if (l15 == 0){
        #pragma unroll
        for (int rt=0;rt<2;++rt)
            #pragma unroll
            for (int i=0;i<4;++i){
                int r = rt*16 + lg*4 + i;
                red[w][r][0] = rsum2[rt][i];
                red[w][r][1] = rsq2[rt][i];
            }
    }
    __syncthreads();

    #pragma unroll
    for (int rt=0;rt<2;++rt)
        #pragma unroll
        for (int i=0;i<4;++i){
            int r = rt*16 + lg*4 + i;
            float S = red[0][r][0]+red[1][r][0]+red[2][r][0]+red[3][r][0];
            float Q = red[0][r][1]+red[1][r][1]+red[2][r][1]+red[3][r][1];
            float mean = S * (1.f/128.f);
            float var  = Q * (1.f/128.f) - mean*mean;
            float rs = rsqrtf(var + LN_EPS);
            size_t gbase = (size_t)(eBase + r)*HD;
            #pragma unroll
            for (int c=0;c<2;++c){
                int colg = w*32 + c*16 + l15;
                float v = (yv[rt][c][i]-mean)*rs*g2c[c] + t2c[c];
                float old = bf2f(ea[gbase + colg]);
                ea[gbase + colg] = f2bf(old + v);
            }
        }
}

// ---------------- fused node update (fp32 VALU; unchanged from passing r4) ----------------
__global__ __launch_bounds__(256) void k_node_update(
    float* __restrict__ h, const ushort_t* __restrict__ ea,
    const int* __restrict__ rowSt, const int* __restrict__ cnt,
    const float* __restrict__ invcnt, const int* __restrict__ edgeIds,
    const float* __restrict__ W1, const float* __restrict__ b1,
    const float* __restrict__ g1, const float* __restrict__ bt1,
    const float* __restrict__ W2, const float* __restrict__ b2,
    const float* __restrict__ g2, const float* __restrict__ bt2)
{
    __shared__ float As[32][256];
    __shared__ float Bs[16][256];

    const int tid = threadIdx.x;
    const int tx = tid & 31;
    const int ty = tid >> 5;
    const int nBase = blockIdx.x * 32;

    #pragma unroll
    for (int it = 0; it < 4; ++it){
        int f = tid + it*256;
        int n = f >> 5;
        int q = f & 31;
        int gn = nBase + n;
        float4 v = make_float4(0.f,0.f,0.f,0.f);
        if (gn < NN) v = *(const float4*)(h + (size_t)gn*HD + q*4);
        *(float4*)&As[n][q*4] = v;
    }
    {
        const int cg  = tid & 127;
        const int grp = tid >> 7;
        for (int i = 0; i < 16; ++i){
            int ln = grp*16 + i;
            int gn = nBase + ln;
            float s = 0.f;
            if (gn < NN){
                int st = rowSt[gn], dg = cnt[gn];
                for (int j = 0; j < dg; ++j){
                    int e = edgeIds[st + j];
                    s += bf2f(ea[(size_t)e*HD + cg]);
                }
                s *= invcnt[gn];
            }
            As[ln][128 + cg] = s;
        }
    }
    __syncthreads();

    float acc[4][8];
    #pragma unroll
    for (int i=0;i<4;++i)
        #pragma unroll
        for (int j=0;j<8;++j) acc[i][j] = 0.f;

    for (int k0 = 0; k0 < 256; k0 += 16){
        #pragma unroll
        for (int it = 0; it < 4; ++it){
            int f = tid + it*256;
            int kk = f >> 6;
            int q  = f & 63;
            *(float4*)&Bs[kk][q*4] = *(const float4*)(W1 + (size_t)(k0+kk)*256 + q*4);
        }
        __syncthreads();
        #pragma unroll
        for (int kk = 0; kk < 16; ++kk){
            float a0 = As[ty*4+0][k0+kk];
            float a1 = As[ty*4+1][k0+kk];
            float a2 = As[ty*4+2][k0+kk];
            float a3 = As[ty*4+3][k0+kk];
            float4 bl = *(float4*)&Bs[kk][tx*8];
            float4 bh = *(float4*)&Bs[kk][tx*8+4];
            float bv[8] = {bl.x,bl.y,bl.z,bl.w,bh.x,bh.y,bh.z,bh.w};
            #pragma unroll
            for (int j=0;j<8;++j){
                acc[0][j] += a0*bv[j];
                acc[1][j] += a1*bv[j];
                acc[2][j] += a2*bv[j];
                acc[3][j] += a3*bv[j];
            }
        }
        __syncthreads();
    }

    float* Ts = &As[0][0];
    const int c0 = tx*8;
    #pragma unroll
    for (int i=0;i<4;++i){
        float v[8]; float es=0.f, es2=0.f;
        #pragma unroll
        for (int j=0;j<8;++j){
            float tv = acc[i][j] + b1[c0+j];
            v[j]=tv; es+=tv; es2+=tv*tv;
        }
        #pragma unroll
        for (int m=1;m<32;m<<=1){ es += __shfl_xor(es,m); es2 += __shfl_xor(es2,m); }
        float mean = es*(1.f/256.f);
        float var  = es2*(1.f/256.f) - mean*mean;
        float rs = rsqrtf(var + LN_EPS);
        #pragma unroll
        for (int j=0;j<8;++j){
            float tv = (v[j]-mean)*rs*g1[c0+j] + bt1[c0+j];
            v[j] = gelu_f(tv);
        }
        *(float4*)&Ts[(ty*4+i)*256 + c0]     = make_float4(v[0],v[1],v[2],v[3]);
        *(float4*)&Ts[(ty*4+i)*256 + c0 + 4] = make_float4(v[4],v[5],v[6],v[7]);
    }
    __syncthreads();

    float acc2[4][4];
    #pragma unroll
    for (int i=0;i<4;++i)
        #pragma unroll
        for (int j=0;j<4;++j) acc2[i][j] = 0.f;
    const int c2 = tx*4;

    for (int k0 = 0; k0 < 256; k0 += 16){
        #pragma unroll
        for (int it = 0; it < 2; ++it){
            int f = tid + it*256;
            int kk = f >> 5;
            int q  = f & 31;
            *(float4*)&Bs[0][kk*128 + q*4] = *(const float4*)(W2 + (size_t)(k0+kk)*128 + q*4);
        }
        __syncthreads();
        #pragma unroll
        for (int kk = 0; kk < 16; ++kk){
            float a0 = Ts[(ty*4+0)*256 + k0+kk];
            float a1 = Ts[(ty*4+1)*256 + k0+kk];
            float a2 = Ts[(ty*4+2)*256 + k0+kk];
            float a3 = Ts[(ty*4+3)*256 + k0+kk];
            float4 b4 = *(float4*)&Bs[0][kk*128 + c2];
            float bv[4] = {b4.x,b4.y,b4.z,b4.w};
            #pragma unroll
            for (int j=0;j<4;++j){
                acc2[0][j] += a0*bv[j];
                acc2[1][j] += a1*bv[j];
                acc2[2][j] += a2*bv[j];
                acc2[3][j] += a3*bv[j];
            }
        }
        __syncthreads();
    }

    #pragma unroll
    for (int i=0;i<4;++i){
        int gn = nBase + ty*4 + i;
        float v[4]; float es=0.f, es2=0.f;
        #pragma unroll
        for (int j=0;j<4;++j){
            float tv = acc2[i][j] + b2[c2+j];
            v[j]=tv; es+=tv; es2+=tv*tv;
        }
        #pragma unroll
        for (int m=1;m<32;m<<=1){ es += __shfl_xor(es,m); es2 += __shfl_xor(es2,m); }
        float mean = es*(1.f/128.f);
        float var  = es2*(1.f/128.f) - mean*mean;
        float rs = rsqrtf(var + LN_EPS);
        if (gn < NN){
            float4 oldv = *(const float4*)(h + (size_t)gn*HD + c2);
            float4 outv;
            outv.x = oldv.x + (v[0]-mean)*rs*g2[c2+0] + bt2[c2+0];
            outv.y = oldv.y + (v[1]-mean)*rs*g2[c2+1] + bt2[c2+1];
            outv.z = oldv.z + (v[2]-mean)*rs*g2[c2+2] + bt2[c2+2];
            outv.w = oldv.w + (v[3]-mean)*rs*g2[c2+3] + bt2[c2+3];
            *(float4*)(h + (size_t)gn*HD + c2) = outv;
        }
    }
}

// ---------------- decoder ----------------
__global__ __launch_bounds__(128) void k_decode(
    const float* __restrict__ h, const float* __restrict__ W1,
    const float* __restrict__ b1, const float* __restrict__ W2,
    const float* __restrict__ b2, float* __restrict__ out)
{
    int n = blockIdx.x, t = threadIdx.x;
    __shared__ float hs[128];
    __shared__ float red[8];
    hs[t] = h[(size_t)n*HD + t];
    __syncthreads();
    float o = b1[t];
    #pragma unroll 8
    for (int k = 0; k < 128; ++k) o += hs[k] * W1[k*128 + t];
    o = gelu_f(o);
    float p0 = o*W2[t*4+0], p1 = o*W2[t*4+1], p2 = o*W2[t*4+2], p3 = o*W2[t*4+3];
    #pragma unroll
    for (int m = 32; m >= 1; m >>= 1){
        p0 += __shfl_xor(p0, m); p1 += __shfl_xor(p1, m);
        p2 += __shfl_xor(p2, m); p3 += __shfl_xor(p3, m);
    }
    int wave = t >> 6;
    if ((t & 63) == 0){ red[wave*4+0]=p0; red[wave*4+1]=p1; red[wave*4+2]=p2; red[wave*4+3]=p3; }
    __syncthreads();
    if (t < 4) out[(size_t)n*4 + t] = red[t] + red[4+t] + b2[t];
}

// ---------------- launch ----------------
extern "C" void kernel_launch(void* const* d_in, const int* in_sizes, int n_in,
                              void* d_out, int out_size, void* d_ws, size_t ws_size,
                              hipStream_t stream)
{
    const float* x      = (const float*)d_in[0];
    const int*   eidx   = (const int*)d_in[1];
    const float* eattr  = (const float*)d_in[2];
    const float* enc_W  = (const float*)d_in[3];
    const float* enc_b  = (const float*)d_in[4];
    const float* enc_g  = (const float*)d_in[5];
    const float* enc_bt = (const float*)d_in[6];
    const float* ee_W   = (const float*)d_in[7];
    const float* ee_b   = (const float*)d_in[8];
    const float* eW1    = (const float*)d_in[9];
    const float* eb1    = (const float*)d_in[10];
    const float* eg1    = (const float*)d_in[11];
    const float* ebt1   = (const float*)d_in[12];
    const float* eW2    = (const float*)d_in[13];
    const float* eb2    = (const float*)d_in[14];
    const float* eg2    = (const float*)d_in[15];
    const float* ebt2   = (const float*)d_in[16];
    const float* nW1    = (const float*)d_in[17];
    const float* nb1    = (const float*)d_in[18];
    const float* ng1    = (const float*)d_in[19];
    const float* nbt1   = (const float*)d_in[20];
    const float* nW2    = (const float*)d_in[21];
    const float* nb2    = (const float*)d_in[22];
    const float* ng2    = (const float*)d_in[23];
    const float* nbt2   = (const float*)d_in[24];
    const float* dec_W1 = (const float*)d_in[25];
    const float* dec_b1 = (const float*)d_in[26];
    const float* dec_W2 = (const float*)d_in[27];
    const float* dec_b2 = (const float*)d_in[28];

    const int* row = eidx;
    const int* col = eidx + NE;

    char* ws0 = (char*)d_ws;
    char* ws = ws0;
    auto alloc = [&](size_t bytes) -> char* {
        char* p = ws;
        ws += (bytes + 255) & ~(size_t)255;
        return p;
    };
    ushort_t* ea      = (ushort_t*)alloc((size_t)NE*HD*2);       // 153.6 MB bf16
    float*    h       = (float*)   alloc((size_t)NN*HD*4);       // 25.6 MB
    ushort_t* W1Tb    = (ushort_t*)alloc((size_t)NL*256*384*2);  // 1.97 MB
    ushort_t* W2Tb    = (ushort_t*)alloc((size_t)NL*128*256*2);  // 0.66 MB
    int*      cnt     = (int*)     alloc((size_t)NN*4);
    int*      rowSt   = (int*)     alloc((size_t)NN*4);
    int*      fill    = (int*)     alloc((size_t)NN*4);
    float*    invcnt  = (float*)   alloc((size_t)NN*4);
    int*      edgeIds = (int*)     alloc((size_t)NE*4);
    int*      bsum    = (int*)     alloc(256*4);
    int*      boff    = (int*)     alloc(256*4);

    size_t need = (size_t)(ws - ws0);
    if (ws_size < need){
        k_sentinel_out<<<(out_size+255)/256, 256, 0, stream>>>((float*)d_out, out_size, 3.0f);
        return;
    }

    hipMemsetAsync(cnt,  0, (size_t)NN*4, stream);
    hipMemsetAsync(fill, 0, (size_t)NN*4, stream);

    k_w1t<<<(NL*256*384+255)/256, 256, 0, stream>>>(eW1, W1Tb);
    k_w2t<<<(NL*128*256+255)/256, 256, 0, stream>>>(eW2, W2Tb);

    k_encode_nodes<<<NN, 128, 0, stream>>>(x, enc_W, enc_b, enc_g, enc_bt, h);
    k_encode_edges<<<NE/2, 256, 0, stream>>>(eattr, ee_W, ee_b, ea);

    k_hist <<<(NE+255)/256, 256, 0, stream>>>(col, cnt);
    k_scan1<<<NBLK, 256, 0, stream>>>(cnt, bsum);
    k_scan2<<<1, 256, 0, stream>>>(bsum, boff);
    k_scan3<<<NBLK, 256, 0, stream>>>(cnt, boff, rowSt, invcnt);
    k_fill <<<(NE+255)/256, 256, 0, stream>>>(col, rowSt, fill, edgeIds);

    for (int l = 0; l < NL; ++l){
        k_edge_update<<<NE/32, 256, 0, stream>>>(h, ea, row, col,
            W1Tb + (size_t)l*256*384, eb1 + l*256, eg1 + l*256, ebt1 + l*256,
            W2Tb + (size_t)l*128*256, eb2 + l*128, eg2 + l*128, ebt2 + l*128);
        k_node_update<<<(NN+31)/32, 256, 0, stream>>>(h, ea, rowSt, cnt, invcnt, edgeIds,
            nW1 + (size_t)l*256*256, nb1 + l*256, ng1 + l*256, nbt1 + l*256,
            nW2 + (size_t)l*256*128, nb2 + l*128, ng2 + l*128, nbt2 + l*128);
    }

    k_decode<<<NN, 128, 0, stream>>>(h, dec_W1, dec_b1, dec_W2, dec_b2, (float*)d_out);
}

// Round 8
// 10151.582 us; speedup vs baseline: 3.1789x; 1.2916x over previous
//
#include <hip/hip_runtime.h>
#include <math.h>

#define NN 50000
#define NE 600000
#define HD 128
#define NL 10
#define LN_EPS 1e-5f
#define SCAN_B 256
#define NBLK ((NN + SCAN_B - 1) / SCAN_B)   // 196

typedef unsigned short ushort_t;
typedef __attribute__((ext_vector_type(8))) short bf16x8;
typedef __attribute__((ext_vector_type(4))) float f32x4;

// fast GELU: x*sigmoid(1.5957691*(x+0.044715*x^3)); |err| vs erf-GELU ~1e-3
__device__ __forceinline__ float gelu_f(float x){
    float x2 = x*x;
    float z  = 1.5957691f*x + 0.07135481f*x2*x;
    float s  = 1.0f/(1.0f + __expf(-z));
    return x*s;
}
__device__ __forceinline__ float bf2f(ushort_t u){
    unsigned int x = ((unsigned int)u) << 16;
    float f; __builtin_memcpy(&f, &x, 4); return f;
}
__device__ __forceinline__ ushort_t f2bf(float f){
    unsigned int x; __builtin_memcpy(&x, &f, 4);
    unsigned int lsb = (x >> 16) & 1u;
    x += 0x7fffu + lsb;                 // round-to-nearest-even
    return (ushort_t)(x >> 16);
}

// ---------------- sentinel fill (ws-too-small diagnostic) ----------------
__global__ void k_sentinel_out(float* __restrict__ out, int n, float v){
    int i = blockIdx.x*256 + threadIdx.x;
    if (i < n) out[i] = v;
}

// ---------------- weight pre-transpose+convert: WT[l][n][k] = bf16(W[l][k][n]) ----------------
__global__ void k_wt(const float* __restrict__ W, ushort_t* __restrict__ WT, int K, int N){
    int idx = blockIdx.x*256 + threadIdx.x;
    if (idx >= NL*K*N) return;
    int l = idx / (K*N);
    int rem = idx - l*(K*N);
    int n = rem / K;
    int k = rem - n*K;
    WT[idx] = f2bf(W[(size_t)l*K*N + (size_t)k*N + n]);
}

// ---------------- encoder: h = gelu(LN(x @ W + b)); writes f32 + bf16 mirror ----------------
__global__ __launch_bounds__(128) void k_encode_nodes(
    const float* __restrict__ x, const float* __restrict__ W,
    const float* __restrict__ b, const float* __restrict__ g,
    const float* __restrict__ beta, float* __restrict__ h, ushort_t* __restrict__ h_bf)
{
    int n = blockIdx.x;
    int t = threadIdx.x;
    __shared__ float xs[7];
    __shared__ float red[4];
    if (t < 7) xs[t] = x[n*7 + t];
    __syncthreads();
    float acc = b[t];
    #pragma unroll
    for (int i = 0; i < 7; ++i) acc += xs[i] * W[i*HD + t];
    float s = acc, s2 = acc*acc;
    #pragma unroll
    for (int m = 32; m >= 1; m >>= 1) { s += __shfl_xor(s, m); s2 += __shfl_xor(s2, m); }
    int wave = t >> 6;
    if ((t & 63) == 0) { red[wave*2] = s; red[wave*2+1] = s2; }
    __syncthreads();
    s = red[0] + red[2]; s2 = red[1] + red[3];
    float mean = s * (1.0f/HD);
    float var  = s2 * (1.0f/HD) - mean*mean;
    float rs = rsqrtf(var + LN_EPS);
    float v = (acc - mean) * rs * g[t] + beta[t];
    float o = gelu_f(v);
    h[(size_t)n*HD + t] = o;
    h_bf[(size_t)n*HD + t] = f2bf(o);
}

// ---------------- edge encoder: ea = attr @ W + b (bf16 store) ----------------
__global__ __launch_bounds__(256) void k_encode_edges(
    const float* __restrict__ attr, const float* __restrict__ W,
    const float* __restrict__ b, ushort_t* __restrict__ ea)
{
    int e = blockIdx.x * 2 + (threadIdx.x >> 7);
    int c = threadIdx.x & 127;
    float acc = b[c];
    #pragma unroll
    for (int i = 0; i < 8; ++i) acc += attr[(size_t)e*8 + i] * W[i*HD + c];
    ea[(size_t)e*HD + c] = f2bf(acc);
}

// ---------------- CSR build ----------------
__global__ void k_hist(const int* __restrict__ col, int* __restrict__ cnt){
    int e = blockIdx.x*256 + threadIdx.x;
    if (e < NE) atomicAdd(&cnt[col[e]], 1);
}

__global__ __launch_bounds__(256) void k_scan1(const int* __restrict__ cnt, int* __restrict__ bsum){
    __shared__ int s[256];
    int i = blockIdx.x*256 + threadIdx.x;
    int t = threadIdx.x;
    s[t] = (i < NN) ? cnt[i] : 0;
    __syncthreads();
    for (int off = 128; off >= 1; off >>= 1){
        if (t < off) s[t] += s[t+off];
        __syncthreads();
    }
    if (t == 0) bsum[blockIdx.x] = s[0];
}

__global__ __launch_bounds__(256) void k_scan2(const int* __restrict__ bsum, int* __restrict__ boff){
    __shared__ int s[256];
    int t = threadIdx.x;
    int v = (t < NBLK) ? bsum[t] : 0;
    s[t] = v; __syncthreads();
    for (int off = 1; off < 256; off <<= 1){
        int tmp = (t >= off) ? s[t-off] : 0;
        __syncthreads();
        s[t] += tmp;
        __syncthreads();
    }
    if (t < NBLK) boff[t] = s[t] - v;   // exclusive
}

__global__ __launch_bounds__(256) void k_scan3(const int* __restrict__ cnt, const int* __restrict__ boff,
        int* __restrict__ rowStart, float* __restrict__ invcnt){
    __shared__ int s[256];
    int i = blockIdx.x*256 + threadIdx.x;
    int t = threadIdx.x;
    int v = (i < NN) ? cnt[i] : 0;
    s[t] = v; __syncthreads();
    for (int off = 1; off < 256; off <<= 1){
        int tmp = (t >= off) ? s[t-off] : 0;
        __syncthreads();
        s[t] += tmp;
        __syncthreads();
    }
    if (i < NN){
        rowStart[i] = boff[blockIdx.x] + s[t] - v;
        invcnt[i]   = 1.0f / fmaxf((float)v, 1.0f);
    }
}

__global__ void k_fill(const int* __restrict__ col, const int* __restrict__ rowStart,
                       int* __restrict__ fill, int* __restrict__ edgeIds){
    int e = blockIdx.x*256 + threadIdx.x;
    if (e < NE){
        int c = col[e];
        int p = rowStart[c] + atomicAdd(&fill[c], 1);
        edgeIds[p] = e;
    }
}

// ---------------- MFMA fused edge update ----------------
// Fragment maps: A: row=lane&15, k=(lane>>4)*8+j.  B: col=lane&15, k=(lane>>4)*8+j.
// C/D: col=lane&15, row=(lane>>4)*4+reg (HW-verified).
#define AP 392   // A LDS row stride (shorts)
#define A2P 264  // A2 row stride (shorts)
__global__ __launch_bounds__(256) void k_edge_update(
    const ushort_t* __restrict__ h_bf, ushort_t* __restrict__ ea,
    const int* __restrict__ row, const int* __restrict__ col,
    const ushort_t* __restrict__ W1T, const float* __restrict__ b1,
    const float* __restrict__ g1, const float* __restrict__ bt1,
    const ushort_t* __restrict__ W2T, const float* __restrict__ b2,
    const float* __restrict__ g2, const float* __restrict__ bt2)
{
    __shared__ short As[32*AP];          // 25088 B; aliased as A2s after phase 1
    __shared__ float red[4][32][2];      // cross-wave LN partials
    __shared__ int ridx[32], cidx[32];

    const int tid  = threadIdx.x;
    const int lane = tid & 63;
    const int w    = tid >> 6;
    const int l15  = lane & 15;
    const int lg   = lane >> 4;
    const int eBase = blockIdx.x * 32;

    if (tid < 32){ ridx[tid] = row[eBase+tid]; cidx[tid] = col[eBase+tid]; }
    __syncthreads();

    // ---- stage A tile: raw bf16 uint4 copies ----
    #pragma unroll
    for (int it = 0; it < 2; ++it){
        int f = tid + it*256;            // 0..511
        int e = f >> 4, q = f & 15;
        uint4 v = *(const uint4*)(h_bf + (size_t)ridx[e]*HD + q*8);
        *(uint4*)&As[e*AP + q*8] = v;
    }
    #pragma unroll
    for (int it = 0; it < 2; ++it){
        int f = tid + it*256;
        int e = f >> 4, q = f & 15;
        uint4 v = *(const uint4*)(h_bf + (size_t)cidx[e]*HD + q*8);
        *(uint4*)&As[e*AP + 128 + q*8] = v;
    }
    #pragma unroll
    for (int it = 0; it < 2; ++it){
        int f = tid + it*256;
        int e = f >> 4, q = f & 15;
        uint4 v = *(const uint4*)(ea + (size_t)(eBase+e)*HD + q*8);
        *(uint4*)&As[e*AP + 256 + q*8] = v;
    }
    __syncthreads();

    // ---- phase 1: (32x384)@(384x256) ----
    f32x4 acc[2][4];
    #pragma unroll
    for (int rt=0;rt<2;++rt)
        #pragma unroll
        for (int c=0;c<4;++c) acc[rt][c] = (f32x4){0.f,0.f,0.f,0.f};

    #pragma unroll 2
    for (int kc = 0; kc < 12; ++kc){
        int k0 = kc*32 + lg*8;
        bf16x8 a0 = *(const bf16x8*)&As[(l15     )*AP + k0];
        bf16x8 a1 = *(const bf16x8*)&As[(l15 + 16)*AP + k0];
        #pragma unroll
        for (int c=0;c<4;++c){
            int colg = w*64 + c*16 + l15;
            bf16x8 b = *(const bf16x8*)&W1T[(size_t)colg*384 + k0];
            acc[0][c] = __builtin_amdgcn_mfma_f32_16x16x32_bf16(a0, b, acc[0][c], 0, 0, 0);
            acc[1][c] = __builtin_amdgcn_mfma_f32_16x16x32_bf16(a1, b, acc[1][c], 0, 0, 0);
        }
    }

    // ---- epilogue 1: +b1, LN(256), GELU -> A2s (bf16) ----
    float b1c[4], g1c[4], t1c[4];
    #pragma unroll
    for (int c=0;c<4;++c){
        int colg = w*64 + c*16 + l15;
        b1c[c] = b1[colg]; g1c[c] = g1[colg]; t1c[c] = bt1[colg];
    }
    float xv[2][4][4];
    #pragma unroll
    for (int rt=0;rt<2;++rt)
        #pragma unroll
        for (int c=0;c<4;++c)
            #pragma unroll
            for (int i=0;i<4;++i) xv[rt][c][i] = acc[rt][c][i] + b1c[c];

    float rsum[2][4], rsq[2][4];
    #pragma unroll
    for (int rt=0;rt<2;++rt)
        #pragma unroll
        for (int i=0;i<4;++i){
            float s=0.f, q=0.f;
            #pragma unroll
            for (int c=0;c<4;++c){ float v=xv[rt][c][i]; s+=v; q+=v*v; }
            #pragma unroll
            for (int m=1;m<16;m<<=1){ s += __shfl_xor(s,m); q += __shfl_xor(q,m); }
            rsum[rt][i]=s; rsq[rt][i]=q;
        }
    if (l15 == 0){
        #pragma unroll
        for (int rt=0;rt<2;++rt)
            #pragma unroll
            for (int i=0;i<4;++i){
                int r = rt*16 + lg*4 + i;
                red[w][r][0] = rsum[rt][i];
                red[w][r][1] = rsq[rt][i];
            }
    }
    __syncthreads();

    short* A2s = &As[0];
    #pragma unroll
    for (int rt=0;rt<2;++rt)
        #pragma unroll
        for (int i=0;i<4;++i){
            int r = rt*16 + lg*4 + i;
            float S = red[0][r][0]+red[1][r][0]+red[2][r][0]+red[3][r][0];
            float Q = red[0][r][1]+red[1][r][1]+red[2][r][1]+red[3][r][1];
            float mean = S * (1.f/256.f);
            float var  = Q * (1.f/256.f) - mean*mean;
            float rs = rsqrtf(var + LN_EPS);
            #pragma unroll
            for (int c=0;c<4;++c){
                int colg = w*64 + c*16 + l15;
                float v = (xv[rt][c][i]-mean)*rs*g1c[c] + t1c[c];
                A2s[r*A2P + colg] = (short)f2bf(gelu_f(v));
            }
        }
    __syncthreads();

    // ---- phase 2: (32x256)@(256x128) ----
    f32x4 acc2[2][2];
    #pragma unroll
    for (int rt=0;rt<2;++rt)
        #pragma unroll
        for (int c=0;c<2;++c) acc2[rt][c] = (f32x4){0.f,0.f,0.f,0.f};

    #pragma unroll 2
    for (int kc = 0; kc < 8; ++kc){
        int k0 = kc*32 + lg*8;
        bf16x8 a0 = *(const bf16x8*)&A2s[(l15     )*A2P + k0];
        bf16x8 a1 = *(const bf16x8*)&A2s[(l15 + 16)*A2P + k0];
        #pragma unroll
        for (int c=0;c<2;++c){
            int colg = w*32 + c*16 + l15;
            bf16x8 b = *(const bf16x8*)&W2T[(size_t)colg*256 + k0];
            acc2[0][c] = __builtin_amdgcn_mfma_f32_16x16x32_bf16(a0, b, acc2[0][c], 0, 0, 0);
            acc2[1][c] = __builtin_amdgcn_mfma_f32_16x16x32_bf16(a1, b, acc2[1][c], 0, 0, 0);
        }
    }

    // ---- epilogue 2: +b2, LN(128), residual into ea (bf16) ----
    float b2c[2], g2c[2], t2c[2];
    #pragma unroll
    for (int c=0;c<2;++c){
        int colg = w*32 + c*16 + l15;
        b2c[c] = b2[colg]; g2c[c] = g2[colg]; t2c[c] = bt2[colg];
    }
    float yv[2][2][4];
    #pragma unroll
    for (int rt=0;rt<2;++rt)
        #pragma unroll
        for (int c=0;c<2;++c)
            #pragma unroll
            for (int i=0;i<4;++i) yv[rt][c][i] = acc2[rt][c][i] + b2c[c];

    float rsum2[2][4], rsq2[2][4];
    #pragma unroll
    for (int rt=0;rt<2;++rt)
        #pragma unroll
        for (int i=0;i<4;++i){
            float s=0.f, q=0.f;
            #pragma unroll
            for (int c=0;c<2;++c){ float v=yv[rt][c][i]; s+=v; q+=v*v; }
            #pragma unroll
            for (int m=1;m<16;m<<=1){ s += __shfl_xor(s,m); q += __shfl_xor(q,m); }
            rsum2[rt][i]=s; rsq2[rt][i]=q;
        }
    __syncthreads();
    if (l15 == 0){
        #pragma unroll
        for (int rt=0;rt<2;++rt)
            #pragma unroll
            for (int i=0;i<4;++i){
                int r = rt*16 + lg*4 + i;
                red[w][r][0] = rsum2[rt][i];
                red[w][r][1] = rsq2[rt][i];
            }
    }
    __syncthreads();

    #pragma unroll
    for (int rt=0;rt<2;++rt)
        #pragma unroll
        for (int i=0;i<4;++i){
            int r = rt*16 + lg*4 + i;
            float S = red[0][r][0]+red[1][r][0]+red[2][r][0]+red[3][r][0];
            float Q = red[0][r][1]+red[1][r][1]+red[2][r][1]+red[3][r][1];
            float mean = S * (1.f/128.f);
            float var  = Q * (1.f/128.f) - mean*mean;
            float rs = rsqrtf(var + LN_EPS);
            size_t gbase = (size_t)(eBase + r)*HD;
            #pragma unroll
            for (int c=0;c<2;++c){
                int colg = w*32 + c*16 + l15;
                float v = (yv[rt][c][i]-mean)*rs*g2c[c] + t2c[c];
                float old = bf2f(ea[gbase + colg]);
                ea[gbase + colg] = f2bf(old + v);
            }
        }
}

// ---------------- MFMA fused node update (agg fused in) ----------------
// A=[h_bf | agg] 32x256 bf16 in LDS; GEMM1 vs nW1T [256][256]; LN+GELU;
// GEMM2 vs nW2T [128][256]; LN + residual -> h (f32) + h_bf.
#define NP 264   // LDS row stride (shorts) for 256-col tiles
__global__ __launch_bounds__(256) void k_node_update(
    float* __restrict__ h, ushort_t* __restrict__ h_bf,
    const ushort_t* __restrict__ ea,
    const int* __restrict__ rowSt, const int* __restrict__ cnt,
    const float* __restrict__ invcnt, const int* __restrict__ edgeIds,
    const ushort_t* __restrict__ W1T, const float* __restrict__ b1,
    const float* __restrict__ g1, const float* __restrict__ bt1,
    const ushort_t* __restrict__ W2T, const float* __restrict__ b2,
    const float* __restrict__ g2, const float* __restrict__ bt2)
{
    __shared__ short As[32*NP];          // 16896 B; reused as A2s after phase 1
    __shared__ float red[4][32][2];

    const int tid  = threadIdx.x;
    const int lane = tid & 63;
    const int w    = tid >> 6;
    const int l15  = lane & 15;
    const int lg   = lane >> 4;
    const int nBase = blockIdx.x * 32;

    // ---- stage h_bf rows (cols 0..127) ----
    #pragma unroll
    for (int it = 0; it < 2; ++it){
        int f = tid + it*256;            // 0..511
        int e = f >> 4, q = f & 15;
        int gn = nBase + e;
        uint4 v = make_uint4(0,0,0,0);
        if (gn < NN) v = *(const uint4*)(h_bf + (size_t)gn*HD + q*8);
        *(uint4*)&As[e*NP + q*8] = v;
    }
    // ---- CSR gather-mean into cols 128..255 (bf16) ----
    {
        const int cg  = tid & 127;
        const int grp = tid >> 7;
        for (int i = 0; i < 16; ++i){
            int ln = grp*16 + i;
            int gn = nBase + ln;
            float s = 0.f;
            if (gn < NN){
                int st = rowSt[gn], dg = cnt[gn];
                for (int j = 0; j < dg; ++j){
                    int e = edgeIds[st + j];
                    s += bf2f(ea[(size_t)e*HD + cg]);
                }
                s *= invcnt[gn];
            }
            As[ln*NP + 128 + cg] = (short)f2bf(s);
        }
    }
    __syncthreads();

    // ---- phase 1: (32x256)@(256x256) ----
    f32x4 acc[2][4];
    #pragma unroll
    for (int rt=0;rt<2;++rt)
        #pragma unroll
        for (int c=0;c<4;++c) acc[rt][c] = (f32x4){0.f,0.f,0.f,0.f};

    #pragma unroll 2
    for (int kc = 0; kc < 8; ++kc){
        int k0 = kc*32 + lg*8;
        bf16x8 a0 = *(const bf16x8*)&As[(l15     )*NP + k0];
        bf16x8 a1 = *(const bf16x8*)&As[(l15 + 16)*NP + k0];
        #pragma unroll
        for (int c=0;c<4;++c){
            int colg = w*64 + c*16 + l15;
            bf16x8 b = *(const bf16x8*)&W1T[(size_t)colg*256 + k0];
            acc[0][c] = __builtin_amdgcn_mfma_f32_16x16x32_bf16(a0, b, acc[0][c], 0, 0, 0);
            acc[1][c] = __builtin_amdgcn_mfma_f32_16x16x32_bf16(a1, b, acc[1][c], 0, 0, 0);
        }
    }

    // ---- epilogue 1: +b1, LN(256), GELU -> A2s ----
    float b1c[4], g1c[4], t1c[4];
    #pragma unroll
    for (int c=0;c<4;++c){
        int colg = w*64 + c*16 + l15;
        b1c[c] = b1[colg]; g1c[c] = g1[colg]; t1c[c] = bt1[colg];
    }
    float xv[2][4][4];
    #pragma unroll
    for (int rt=0;rt<2;++rt)
        #pragma unroll
        for (int c=0;c<4;++c)
            #pragma unroll
            for (int i=0;i<4;++i) xv[rt][c][i] = acc[rt][c][i] + b1c[c];

    float rsum[2][4], rsq[2][4];
    #pragma unroll
    for (int rt=0;rt<2;++rt)
        #pragma unroll
        for (int i=0;i<4;++i){
            float s=0.f, q=0.f;
            #pragma unroll
            for (int c=0;c<4;++c){ float v=xv[rt][c][i]; s+=v; q+=v*v; }
            #pragma unroll
            for (int m=1;m<16;m<<=1){ s += __shfl_xor(s,m); q += __shfl_xor(q,m); }
            rsum[rt][i]=s; rsq[rt][i]=q;
        }
    if (l15 == 0){
        #pragma unroll
        for (int rt=0;rt<2;++rt)
            #pragma unroll
            for (int i=0;i<4;++i){
                int r = rt*16 + lg*4 + i;
                red[w][r][0] = rsum[rt][i];
                red[w][r][1] = rsq[rt][i];
            }
    }
    __syncthreads();

    short* A2s = &As[0];
    #pragma unroll
    for (int rt=0;rt<2;++rt)
        #pragma unroll
        for (int i=0;i<4;++i){
            int r = rt*16 + lg*4 + i;
            float S = red[0][r][0]+red[1][r][0]+red[2][r][0]+red[3][r][0];
            float Q = red[0][r][1]+red[1][r][1]+red[2][r][1]+red[3][r][1];
            float mean = S * (1.f/256.f);
            float var  = Q * (1.f/256.f) - mean*mean;
            float rs = rsqrtf(var + LN_EPS);
            #pragma unroll
            for (int c=0;c<4;++c){
                int colg = w*64 + c*16 + l15;
                float v = (xv[rt][c][i]-mean)*rs*g1c[c] + t1c[c];
                A2s[r*NP + colg] = (short)f2bf(gelu_f(v));
            }
        }
    __syncthreads();

    // ---- phase 2: (32x256)@(256x128) ----
    f32x4 acc2[2][2];
    #pragma unroll
    for (int rt=0;rt<2;++rt)
        #pragma unroll
        for (int c=0;c<2;++c) acc2[rt][c] = (f32x4){0.f,0.f,0.f,0.f};

    #pragma unroll 2
    for (int kc = 0; kc < 8; ++kc){
        int k0 = kc*32 + lg*8;
        bf16x8 a0 = *(const bf16x8*)&A2s[(l15     )*NP + k0];
        bf16x8 a1 = *(const bf16x8*)&A2s[(l15 + 16)*NP + k0];
        #pragma unroll
        for (int c=0;c<2;++c){
            int colg = w*32 + c*16 + l15;
            bf16x8 b = *(const bf16x8*)&W2T[(size_t)colg*256 + k0];
            acc2[0][c] = __builtin_amdgcn_mfma_f32_16x16x32_bf16(a0, b, acc2[0][c], 0, 0, 0);
            acc2[1][c] = __builtin_amdgcn_mfma_f32_16x16x32_bf16(a1, b, acc2[1][c], 0, 0, 0);
        }
    }

    // ---- epilogue 2: +b2, LN(128), residual -> h + h_bf ----
    float b2c[2], g2c[2], t2c[2];
    #pragma unroll
    for (int c=0;c<2;++c){
        int colg = w*32 + c*16 + l15;
        b2c[c] = b2[colg]; g2c[c] = g2[colg]; t2c[c] = bt2[colg];
    }
    float yv[2][2][4];
    #pragma unroll
    for (int rt=0;rt<2;++rt)
        #pragma unroll
        for (int c=0;c<2;++c)
            #pragma unroll
            for (int i=0;i<4;++i) yv[rt][c][i] = acc2[rt][c][i] + b2c[c];

    float rsum2[2][4], rsq2[2][4];
    #pragma unroll
    for (int rt=0;rt<2;++rt)
        #pragma unroll
        for (int i=0;i<4;++i){
            float s=0.f, q=0.f;
            #pragma unroll
            for (int c=0;c<2;++c){ float v=yv[rt][c][i]; s+=v; q+=v*v; }
            #pragma unroll
            for (int m=1;m<16;m<<=1){ s += __shfl_xor(s,m); q += __shfl_xor(q,m); }
            rsum2[rt][i]=s; rsq2[rt][i]=q;
        }
    __syncthreads();
    if (l15 == 0){
        #pragma unroll
        for (int rt=0;rt<2;++rt)
            #pragma unroll
            for (int i=0;i<4;++i){
                int r = rt*16 + lg*4 + i;
                red[w][r][0] = rsum2[rt][i];
                red[w][r][1] = rsq2[rt][i];
            }
    }
    __syncthreads();

    #pragma unroll
    for (int rt=0;rt<2;++rt)
        #pragma unroll
        for (int i=0;i<4;++i){
            int r = rt*16 + lg*4 + i;
            int gn = nBase + r;
            if (gn < NN){
                float S = red[0][r][0]+red[1][r][0]+red[2][r][0]+red[3][r][0];
                float Q = red[0][r][1]+red[1][r][1]+red[2][r][1]+red[3][r][1];
                float mean = S * (1.f/128.f);
                float var  = Q * (1.f/128.f) - mean*mean;
                float rs = rsqrtf(var + LN_EPS);
                size_t gbase = (size_t)gn*HD;
                #pragma unroll
                for (int c=0;c<2;++c){
                    int colg = w*32 + c*16 + l15;
                    float v = (yv[rt][c][i]-mean)*rs*g2c[c] + t2c[c];
                    float nv = h[gbase + colg] + v;
                    h[gbase + colg] = nv;
                    h_bf[gbase + colg] = f2bf(nv);
                }
            }
        }
}

// ---------------- decoder ----------------
__global__ __launch_bounds__(128) void k_decode(
    const float* __restrict__ h, const float* __restrict__ W1,
    const float* __restrict__ b1, const float* __restrict__ W2,
    const float* __restrict__ b2, float* __restrict__ out)
{
    int n = blockIdx.x, t = threadIdx.x;
    __shared__ float hs[128];
    __shared__ float red[8];
    hs[t] = h[(size_t)n*HD + t];
    __syncthreads();
    float o = b1[t];
    #pragma unroll 8
    for (int k = 0; k < 128; ++k) o += hs[k] * W1[k*128 + t];
    o = gelu_f(o);
    float p0 = o*W2[t*4+0], p1 = o*W2[t*4+1], p2 = o*W2[t*4+2], p3 = o*W2[t*4+3];
    #pragma unroll
    for (int m = 32; m >= 1; m >>= 1){
        p0 += __shfl_xor(p0, m); p1 += __shfl_xor(p1, m);
        p2 += __shfl_xor(p2, m); p3 += __shfl_xor(p3, m);
    }
    int wave = t >> 6;
    if ((t & 63) == 0){ red[wave*4+0]=p0; red[wave*4+1]=p1; red[wave*4+2]=p2; red[wave*4+3]=p3; }
    __syncthreads();
    if (t < 4) out[(size_t)n*4 + t] = red[t] + red[4+t] + b2[t];
}

// ---------------- launch ----------------
extern "C" void kernel_launch(void* const* d_in, const int* in_sizes, int n_in,
                              void* d_out, int out_size, void* d_ws, size_t ws_size,
                              hipStream_t stream)
{
    const float* x      = (const float*)d_in[0];
    const int*   eidx   = (const int*)d_in[1];
    const float* eattr  = (const float*)d_in[2];
    const float* enc_W  = (const float*)d_in[3];
    const float* enc_b  = (const float*)d_in[4];
    const float* enc_g  = (const float*)d_in[5];
    const float* enc_bt = (const float*)d_in[6];
    const float* ee_W   = (const float*)d_in[7];
    const float* ee_b   = (const float*)d_in[8];
    const float* eW1    = (const float*)d_in[9];
    const float* eb1    = (const float*)d_in[10];
    const float* eg1    = (const float*)d_in[11];
    const float* ebt1   = (const float*)d_in[12];
    const float* eW2    = (const float*)d_in[13];
    const float* eb2    = (const float*)d_in[14];
    const float* eg2    = (const float*)d_in[15];
    const float* ebt2   = (const float*)d_in[16];
    const float* nW1    = (const float*)d_in[17];
    const float* nb1    = (const float*)d_in[18];
    const float* ng1    = (const float*)d_in[19];
    const float* nbt1   = (const float*)d_in[20];
    const float* nW2    = (const float*)d_in[21];
    const float* nb2    = (const float*)d_in[22];
    const float* ng2    = (const float*)d_in[23];
    const float* nbt2   = (const float*)d_in[24];
    const float* dec_W1 = (const float*)d_in[25];
    const float* dec_b1 = (const float*)d_in[26];
    const float* dec_W2 = (const float*)d_in[27];
    const float* dec_b2 = (const float*)d_in[28];

    const int* row = eidx;
    const int* col = eidx + NE;

    char* ws0 = (char*)d_ws;
    char* ws = ws0;
    auto alloc = [&](size_t bytes) -> char* {
        char* p = ws;
        ws += (bytes + 255) & ~(size_t)255;
        return p;
    };
    ushort_t* ea      = (ushort_t*)alloc((size_t)NE*HD*2);       // 153.6 MB
    float*    h       = (float*)   alloc((size_t)NN*HD*4);       // 25.6 MB
    ushort_t* h_bf    = (ushort_t*)alloc((size_t)NN*HD*2);       // 12.8 MB
    ushort_t* W1Tb    = (ushort_t*)alloc((size_t)NL*256*384*2);  // 1.97 MB
    ushort_t* W2Tb    = (ushort_t*)alloc((size_t)NL*128*256*2);  // 0.66 MB
    ushort_t* nW1Tb   = (ushort_t*)alloc((size_t)NL*256*256*2);  // 1.31 MB
    ushort_t* nW2Tb   = (ushort_t*)alloc((size_t)NL*128*256*2);  // 0.66 MB
    int*      cnt     = (int*)     alloc((size_t)NN*4);
    int*      rowSt   = (int*)     alloc((size_t)NN*4);
    int*      fill    = (int*)     alloc((size_t)NN*4);
    float*    invcnt  = (float*)   alloc((size_t)NN*4);
    int*      edgeIds = (int*)     alloc((size_t)NE*4);
    int*      bsum    = (int*)     alloc(256*4);
    int*      boff    = (int*)     alloc(256*4);

    size_t need = (size_t)(ws - ws0);
    if (ws_size < need){
        k_sentinel_out<<<(out_size+255)/256, 256, 0, stream>>>((float*)d_out, out_size, 3.0f);
        return;
    }

    hipMemsetAsync(cnt,  0, (size_t)NN*4, stream);
    hipMemsetAsync(fill, 0, (size_t)NN*4, stream);

    k_wt<<<(NL*384*256+255)/256, 256, 0, stream>>>(eW1, W1Tb, 384, 256);
    k_wt<<<(NL*256*128+255)/256, 256, 0, stream>>>(eW2, W2Tb, 256, 128);
    k_wt<<<(NL*256*256+255)/256, 256, 0, stream>>>(nW1, nW1Tb, 256, 256);
    k_wt<<<(NL*256*128+255)/256, 256, 0, stream>>>(nW2, nW2Tb, 256, 128);

    k_encode_nodes<<<NN, 128, 0, stream>>>(x, enc_W, enc_b, enc_g, enc_bt, h, h_bf);
    k_encode_edges<<<NE/2, 256, 0, stream>>>(eattr, ee_W, ee_b, ea);

    k_hist <<<(NE+255)/256, 256, 0, stream>>>(col, cnt);
    k_scan1<<<NBLK, 256, 0, stream>>>(cnt, bsum);
    k_scan2<<<1, 256, 0, stream>>>(bsum, boff);
    k_scan3<<<NBLK, 256, 0, stream>>>(cnt, boff, rowSt, invcnt);
    k_fill <<<(NE+255)/256, 256, 0, stream>>>(col, rowSt, fill, edgeIds);

    for (int l = 0; l < NL; ++l){
        k_edge_update<<<NE/32, 256, 0, stream>>>(h_bf, ea, row, col,
            W1Tb + (size_t)l*256*384, eb1 + l*256, eg1 + l*256, ebt1 + l*256,
            W2Tb + (size_t)l*128*256, eb2 + l*128, eg2 + l*128, ebt2 + l*128);
        k_node_update<<<(NN+31)/32, 256, 0, stream>>>(h, h_bf, ea, rowSt, cnt, invcnt, edgeIds,
            nW1Tb + (size_t)l*256*256, nb1 + l*256, ng1 + l*256, nbt1 + l*256,
            nW2Tb + (size_t)l*128*256, nb2 + l*128, ng2 + l*128, nbt2 + l*128);
    }

    k_decode<<<NN, 128, 0, stream>>>(h, dec_W1, dec_b1, dec_W2, dec_b2, (float*)d_out);
}

// Round 9
// 7226.101 us; speedup vs baseline: 4.4658x; 1.4048x over previous
//
#include <hip/hip_runtime.h>
#include <math.h>

#define NN 50000
#define NE 600000
#define HD 128
#define NL 10
#define LN_EPS 1e-5f
#define SCAN_B 256
#define NBLK ((NN + SCAN_B - 1) / SCAN_B)   // 196

typedef unsigned short ushort_t;
typedef __attribute__((ext_vector_type(8))) short bf16x8;
typedef __attribute__((ext_vector_type(4))) float f32x4;

// fast GELU: x*sigmoid(1.5957691*(x+0.044715*x^3)); |err| vs erf-GELU ~1e-3
__device__ __forceinline__ float gelu_f(float x){
    float x2 = x*x;
    float z  = 1.5957691f*x + 0.07135481f*x2*x;
    float s  = 1.0f/(1.0f + __expf(-z));
    return x*s;
}
__device__ __forceinline__ float bf2f(ushort_t u){
    unsigned int x = ((unsigned int)u) << 16;
    float f; __builtin_memcpy(&f, &x, 4); return f;
}
__device__ __forceinline__ ushort_t f2bf(float f){
    unsigned int x; __builtin_memcpy(&x, &f, 4);
    unsigned int lsb = (x >> 16) & 1u;
    x += 0x7fffu + lsb;                 // round-to-nearest-even
    return (ushort_t)(x >> 16);
}

// ---------------- sentinel fill (ws-too-small diagnostic) ----------------
__global__ void k_sentinel_out(float* __restrict__ out, int n, float v){
    int i = blockIdx.x*256 + threadIdx.x;
    if (i < n) out[i] = v;
}

// ---------------- weight pre-transpose+convert: WT[l][n][k] = bf16(W[l][k][n]) ----------------
__global__ void k_wt(const float* __restrict__ W, ushort_t* __restrict__ WT, int K, int N){
    int idx = blockIdx.x*256 + threadIdx.x;
    if (idx >= NL*K*N) return;
    int l = idx / (K*N);
    int rem = idx - l*(K*N);
    int n = rem / K;
    int k = rem - n*K;
    WT[idx] = f2bf(W[(size_t)l*K*N + (size_t)k*N + n]);
}

// ---------------- encoder: h = gelu(LN(x @ W + b)); writes f32 + bf16 mirror ----------------
__global__ __launch_bounds__(128) void k_encode_nodes(
    const float* __restrict__ x, const float* __restrict__ W,
    const float* __restrict__ b, const float* __restrict__ g,
    const float* __restrict__ beta, float* __restrict__ h, ushort_t* __restrict__ h_bf)
{
    int n = blockIdx.x;
    int t = threadIdx.x;
    __shared__ float xs[7];
    __shared__ float red[4];
    if (t < 7) xs[t] = x[n*7 + t];
    __syncthreads();
    float acc = b[t];
    #pragma unroll
    for (int i = 0; i < 7; ++i) acc += xs[i] * W[i*HD + t];
    float s = acc, s2 = acc*acc;
    #pragma unroll
    for (int m = 32; m >= 1; m >>= 1) { s += __shfl_xor(s, m); s2 += __shfl_xor(s2, m); }
    int wave = t >> 6;
    if ((t & 63) == 0) { red[wave*2] = s; red[wave*2+1] = s2; }
    __syncthreads();
    s = red[0] + red[2]; s2 = red[1] + red[3];
    float mean = s * (1.0f/HD);
    float var  = s2 * (1.0f/HD) - mean*mean;
    float rs = rsqrtf(var + LN_EPS);
    float v = (acc - mean) * rs * g[t] + beta[t];
    float o = gelu_f(v);
    h[(size_t)n*HD + t] = o;
    h_bf[(size_t)n*HD + t] = f2bf(o);
}

// ---------------- edge encoder: ea = attr @ W + b (bf16 store) ----------------
__global__ __launch_bounds__(256) void k_encode_edges(
    const float* __restrict__ attr, const float* __restrict__ W,
    const float* __restrict__ b, ushort_t* __restrict__ ea)
{
    int e = blockIdx.x * 2 + (threadIdx.x >> 7);
    int c = threadIdx.x & 127;
    float acc = b[c];
    #pragma unroll
    for (int i = 0; i < 8; ++i) acc += attr[(size_t)e*8 + i] * W[i*HD + c];
    ea[(size_t)e*HD + c] = f2bf(acc);
}

// ---------------- CSR build ----------------
__global__ void k_hist(const int* __restrict__ col, int* __restrict__ cnt){
    int e = blockIdx.x*256 + threadIdx.x;
    if (e < NE) atomicAdd(&cnt[col[e]], 1);
}

__global__ __launch_bounds__(256) void k_scan1(const int* __restrict__ cnt, int* __restrict__ bsum){
    __shared__ int s[256];
    int i = blockIdx.x*256 + threadIdx.x;
    int t = threadIdx.x;
    s[t] = (i < NN) ? cnt[i] : 0;
    __syncthreads();
    for (int off = 128; off >= 1; off >>= 1){
        if (t < off) s[t] += s[t+off];
        __syncthreads();
    }
    if (t == 0) bsum[blockIdx.x] = s[0];
}

__global__ __launch_bounds__(256) void k_scan2(const int* __restrict__ bsum, int* __restrict__ boff){
    __shared__ int s[256];
    int t = threadIdx.x;
    int v = (t < NBLK) ? bsum[t] : 0;
    s[t] = v; __syncthreads();
    for (int off = 1; off < 256; off <<= 1){
        int tmp = (t >= off) ? s[t-off] : 0;
        __syncthreads();
        s[t] += tmp;
        __syncthreads();
    }
    if (t < NBLK) boff[t] = s[t] - v;   // exclusive
}

__global__ __launch_bounds__(256) void k_scan3(const int* __restrict__ cnt, const int* __restrict__ boff,
        int* __restrict__ rowStart, float* __restrict__ invcnt){
    __shared__ int s[256];
    int i = blockIdx.x*256 + threadIdx.x;
    int t = threadIdx.x;
    int v = (i < NN) ? cnt[i] : 0;
    s[t] = v; __syncthreads();
    for (int off = 1; off < 256; off <<= 1){
        int tmp = (t >= off) ? s[t-off] : 0;
        __syncthreads();
        s[t] += tmp;
        __syncthreads();
    }
    if (i < NN){
        rowStart[i] = boff[blockIdx.x] + s[t] - v;
        invcnt[i]   = 1.0f / fmaxf((float)v, 1.0f);
    }
}

__global__ void k_fill(const int* __restrict__ col, const int* __restrict__ rowStart,
                       int* __restrict__ fill, int* __restrict__ edgeIds){
    int e = blockIdx.x*256 + threadIdx.x;
    if (e < NE){
        int c = col[e];
        int p = rowStart[c] + atomicAdd(&fill[c], 1);
        edgeIds[p] = e;
    }
}

// ---------------- MFMA fused edge update (64 edges/block) ----------------
// Fragment maps: A: row=lane&15 (+16*rt), k=(lane>>4)*8+j.  B: col=lane&15, k=(lane>>4)*8+j.
// C/D: col=lane&15, row=(lane>>4)*4+reg (HW-verified).
#define EB 64    // edges per block
#define AP 392   // A LDS row stride (shorts)
#define A2P 264  // A2 row stride (shorts)
__global__ __launch_bounds__(256) void k_edge_update(
    const ushort_t* __restrict__ h_bf, ushort_t* __restrict__ ea,
    const int* __restrict__ row, const int* __restrict__ col,
    const ushort_t* __restrict__ W1T, const float* __restrict__ b1,
    const float* __restrict__ g1, const float* __restrict__ bt1,
    const ushort_t* __restrict__ W2T, const float* __restrict__ b2,
    const float* __restrict__ g2, const float* __restrict__ bt2)
{
    __shared__ short As[EB*AP];          // 50176 B; aliased as A2s after phase 1
    __shared__ float red[4][EB][2];      // 2 KB cross-wave LN partials
    __shared__ int ridx[EB], cidx[EB];

    const int tid  = threadIdx.x;
    const int lane = tid & 63;
    const int w    = tid >> 6;
    const int l15  = lane & 15;
    const int lg   = lane >> 4;
    const int eBase = blockIdx.x * EB;

    if (tid < EB){ ridx[tid] = row[eBase+tid]; cidx[tid] = col[eBase+tid]; }
    __syncthreads();

    // ---- stage A tile: raw bf16 uint4 copies (64 edges x 16 uint4 per segment) ----
    #pragma unroll
    for (int it = 0; it < 4; ++it){
        int f = tid + it*256;            // 0..1023
        int e = f >> 4, q = f & 15;
        uint4 v = *(const uint4*)(h_bf + (size_t)ridx[e]*HD + q*8);
        *(uint4*)&As[e*AP + q*8] = v;
    }
    #pragma unroll
    for (int it = 0; it < 4; ++it){
        int f = tid + it*256;
        int e = f >> 4, q = f & 15;
        uint4 v = *(const uint4*)(h_bf + (size_t)cidx[e]*HD + q*8);
        *(uint4*)&As[e*AP + 128 + q*8] = v;
    }
    #pragma unroll
    for (int it = 0; it < 4; ++it){
        int f = tid + it*256;
        int e = f >> 4, q = f & 15;
        uint4 v = *(const uint4*)(ea + (size_t)(eBase+e)*HD + q*8);
        *(uint4*)&As[e*AP + 256 + q*8] = v;
    }
    __syncthreads();

    // ---- phase 1: (64x384)@(384x256) ----
    f32x4 acc[4][4];
    #pragma unroll
    for (int rt=0;rt<4;++rt)
        #pragma unroll
        for (int c=0;c<4;++c) acc[rt][c] = (f32x4){0.f,0.f,0.f,0.f};

    #pragma unroll 2
    for (int kc = 0; kc < 12; ++kc){
        int k0 = kc*32 + lg*8;
        bf16x8 a[4];
        #pragma unroll
        for (int rt=0;rt<4;++rt) a[rt] = *(const bf16x8*)&As[(l15 + 16*rt)*AP + k0];
        #pragma unroll
        for (int c=0;c<4;++c){
            int colg = w*64 + c*16 + l15;
            bf16x8 b = *(const bf16x8*)&W1T[(size_t)colg*384 + k0];
            #pragma unroll
            for (int rt=0;rt<4;++rt)
                acc[rt][c] = __builtin_amdgcn_mfma_f32_16x16x32_bf16(a[rt], b, acc[rt][c], 0, 0, 0);
        }
    }

    // ---- epilogue 1: +b1, LN(256), GELU -> A2s (bf16) ----
    float b1c[4], g1c[4], t1c[4];
    #pragma unroll
    for (int c=0;c<4;++c){
        int colg = w*64 + c*16 + l15;
        b1c[c] = b1[colg]; g1c[c] = g1[colg]; t1c[c] = bt1[colg];
    }
    float xv[4][4][4];
    #pragma unroll
    for (int rt=0;rt<4;++rt)
        #pragma unroll
        for (int c=0;c<4;++c)
            #pragma unroll
            for (int i=0;i<4;++i) xv[rt][c][i] = acc[rt][c][i] + b1c[c];

    #pragma unroll
    for (int rt=0;rt<4;++rt)
        #pragma unroll
        for (int i=0;i<4;++i){
            float s=0.f, q=0.f;
            #pragma unroll
            for (int c=0;c<4;++c){ float v=xv[rt][c][i]; s+=v; q+=v*v; }
            #pragma unroll
            for (int m=1;m<16;m<<=1){ s += __shfl_xor(s,m); q += __shfl_xor(q,m); }
            if (l15 == 0){
                int r = rt*16 + lg*4 + i;
                red[w][r][0] = s;
                red[w][r][1] = q;
            }
        }
    __syncthreads();   // also guarantees all phase-1 LDS reads done before A2s overwrite

    short* A2s = &As[0];
    #pragma unroll
    for (int rt=0;rt<4;++rt)
        #pragma unroll
        for (int i=0;i<4;++i){
            int r = rt*16 + lg*4 + i;
            float S = red[0][r][0]+red[1][r][0]+red[2][r][0]+red[3][r][0];
            float Q = red[0][r][1]+red[1][r][1]+red[2][r][1]+red[3][r][1];
            float mean = S * (1.f/256.f);
            float var  = Q * (1.f/256.f) - mean*mean;
            float rs = rsqrtf(var + LN_EPS);
            #pragma unroll
            for (int c=0;c<4;++c){
                int colg = w*64 + c*16 + l15;
                float v = (xv[rt][c][i]-mean)*rs*g1c[c] + t1c[c];
                A2s[r*A2P + colg] = (short)f2bf(gelu_f(v));
            }
        }
    __syncthreads();

    // ---- phase 2: (64x256)@(256x128) ----
    f32x4 acc2[4][2];
    #pragma unroll
    for (int rt=0;rt<4;++rt)
        #pragma unroll
        for (int c=0;c<2;++c) acc2[rt][c] = (f32x4){0.f,0.f,0.f,0.f};

    #pragma unroll 2
    for (int kc = 0; kc < 8; ++kc){
        int k0 = kc*32 + lg*8;
        bf16x8 a[4];
        #pragma unroll
        for (int rt=0;rt<4;++rt) a[rt] = *(const bf16x8*)&A2s[(l15 + 16*rt)*A2P + k0];
        #pragma unroll
        for (int c=0;c<2;++c){
            int colg = w*32 + c*16 + l15;
            bf16x8 b = *(const bf16x8*)&W2T[(size_t)colg*256 + k0];
            #pragma unroll
            for (int rt=0;rt<4;++rt)
                acc2[rt][c] = __builtin_amdgcn_mfma_f32_16x16x32_bf16(a[rt], b, acc2[rt][c], 0, 0, 0);
        }
    }

    // ---- epilogue 2: +b2, LN(128), residual into ea (bf16) ----
    float b2c[2], g2c[2], t2c[2];
    #pragma unroll
    for (int c=0;c<2;++c){
        int colg = w*32 + c*16 + l15;
        b2c[c] = b2[colg]; g2c[c] = g2[colg]; t2c[c] = bt2[colg];
    }
    float yv[4][2][4];
    #pragma unroll
    for (int rt=0;rt<4;++rt)
        #pragma unroll
        for (int c=0;c<2;++c)
            #pragma unroll
            for (int i=0;i<4;++i) yv[rt][c][i] = acc2[rt][c][i] + b2c[c];

    __syncthreads();   // ensure epi-1 red reads done before reuse
    #pragma unroll
    for (int rt=0;rt<4;++rt)
        #pragma unroll
        for (int i=0;i<4;++i){
            float s=0.f, q=0.f;
            #pragma unroll
            for (int c=0;c<2;++c){ float v=yv[rt][c][i]; s+=v; q+=v*v; }
            #pragma unroll
            for (int m=1;m<16;m<<=1){ s += __shfl_xor(s,m); q += __shfl_xor(q,m); }
            if (l15 == 0){
                int r = rt*16 + lg*4 + i;
                red[w][r][0] = s;
                red[w][r][1] = q;
            }
        }
    __syncthreads();

    #pragma unroll
    for (int rt=0;rt<4;++rt)
        #pragma unroll
        for (int i=0;i<4;++i){
            int r = rt*16 + lg*4 + i;
            float S = red[0][r][0]+red[1][r][0]+red[2][r][0]+red[3][r][0];
            float Q = red[0][r][1]+red[1][r][1]+red[2][r][1]+red[3][r][1];
            float mean = S * (1.f/128.f);
            float var  = Q * (1.f/128.f) - mean*mean;
            float rs = rsqrtf(var + LN_EPS);
            size_t gbase = (size_t)(eBase + r)*HD;
            #pragma unroll
            for (int c=0;c<2;++c){
                int colg = w*32 + c*16 + l15;
                float v = (yv[rt][c][i]-mean)*rs*g2c[c] + t2c[c];
                float old = bf2f(ea[gbase + colg]);
                ea[gbase + colg] = f2bf(old + v);
            }
        }
}

// ---------------- MFMA fused node update (agg fused in, gather unrolled x4) ----------------
#define NP 264   // LDS row stride (shorts) for 256-col tiles
__global__ __launch_bounds__(256) void k_node_update(
    float* __restrict__ h, ushort_t* __restrict__ h_bf,
    const ushort_t* __restrict__ ea,
    const int* __restrict__ rowSt, const int* __restrict__ cnt,
    const float* __restrict__ invcnt, const int* __restrict__ edgeIds,
    const ushort_t* __restrict__ W1T, const float* __restrict__ b1,
    const float* __restrict__ g1, const float* __restrict__ bt1,
    const ushort_t* __restrict__ W2T, const float* __restrict__ b2,
    const float* __restrict__ g2, const float* __restrict__ bt2)
{
    __shared__ short As[32*NP];          // 16896 B; reused as A2s after phase 1
    __shared__ float red[4][32][2];

    const int tid  = threadIdx.x;
    const int lane = tid & 63;
    const int w    = tid >> 6;
    const int l15  = lane & 15;
    const int lg   = lane >> 4;
    const int nBase = blockIdx.x * 32;

    // ---- stage h_bf rows (cols 0..127) ----
    #pragma unroll
    for (int it = 0; it < 2; ++it){
        int f = tid + it*256;            // 0..511
        int e = f >> 4, q = f & 15;
        int gn = nBase + e;
        uint4 v = make_uint4(0,0,0,0);
        if (gn < NN) v = *(const uint4*)(h_bf + (size_t)gn*HD + q*8);
        *(uint4*)&As[e*NP + q*8] = v;
    }
    // ---- CSR gather-mean into cols 128..255 (bf16), 4-way unrolled ----
    {
        const int cg  = tid & 127;
        const int grp = tid >> 7;
        for (int i = 0; i < 16; ++i){
            int ln = grp*16 + i;
            int gn = nBase + ln;
            float s = 0.f;
            if (gn < NN){
                int st = rowSt[gn], dg = cnt[gn];
                int j = 0;
                for (; j + 4 <= dg; j += 4){
                    int e0 = edgeIds[st+j+0];
                    int e1 = edgeIds[st+j+1];
                    int e2 = edgeIds[st+j+2];
                    int e3 = edgeIds[st+j+3];
                    float v0 = bf2f(ea[(size_t)e0*HD + cg]);
                    float v1 = bf2f(ea[(size_t)e1*HD + cg]);
                    float v2 = bf2f(ea[(size_t)e2*HD + cg]);
                    float v3 = bf2f(ea[(size_t)e3*HD + cg]);
                    s += (v0 + v1) + (v2 + v3);
                }
                for (; j < dg; ++j)
                    s += bf2f(ea[(size_t)edgeIds[st+j]*HD + cg]);
                s *= invcnt[gn];
            }
            As[ln*NP + 128 + cg] = (short)f2bf(s);
        }
    }
    __syncthreads();

    // ---- phase 1: (32x256)@(256x256) ----
    f32x4 acc[2][4];
    #pragma unroll
    for (int rt=0;rt<2;++rt)
        #pragma unroll
        for (int c=0;c<4;++c) acc[rt][c] = (f32x4){0.f,0.f,0.f,0.f};

    #pragma unroll 2
    for (int kc = 0; kc < 8; ++kc){
        int k0 = kc*32 + lg*8;
        bf16x8 a0 = *(const bf16x8*)&As[(l15     )*NP + k0];
        bf16x8 a1 = *(const bf16x8*)&As[(l15 + 16)*NP + k0];
        #pragma unroll
        for (int c=0;c<4;++c){
            int colg = w*64 + c*16 + l15;
            bf16x8 b = *(const bf16x8*)&W1T[(size_t)colg*256 + k0];
            acc[0][c] = __builtin_amdgcn_mfma_f32_16x16x32_bf16(a0, b, acc[0][c], 0, 0, 0);
            acc[1][c] = __builtin_amdgcn_mfma_f32_16x16x32_bf16(a1, b, acc[1][c], 0, 0, 0);
        }
    }

    // ---- epilogue 1: +b1, LN(256), GELU -> A2s ----
    float b1c[4], g1c[4], t1c[4];
    #pragma unroll
    for (int c=0;c<4;++c){
        int colg = w*64 + c*16 + l15;
        b1c[c] = b1[colg]; g1c[c] = g1[colg]; t1c[c] = bt1[colg];
    }
    float xv[2][4][4];
    #pragma unroll
    for (int rt=0;rt<2;++rt)
        #pragma unroll
        for (int c=0;c<4;++c)
            #pragma unroll
            for (int i=0;i<4;++i) xv[rt][c][i] = acc[rt][c][i] + b1c[c];

    #pragma unroll
    for (int rt=0;rt<2;++rt)
        #pragma unroll
        for (int i=0;i<4;++i){
            float s=0.f, q=0.f;
            #pragma unroll
            for (int c=0;c<4;++c){ float v=xv[rt][c][i]; s+=v; q+=v*v; }
            #pragma unroll
            for (int m=1;m<16;m<<=1){ s += __shfl_xor(s,m); q += __shfl_xor(q,m); }
            if (l15 == 0){
                int r = rt*16 + lg*4 + i;
                red[w][r][0] = s;
                red[w][r][1] = q;
            }
        }
    __syncthreads();

    short* A2s = &As[0];
    #pragma unroll
    for (int rt=0;rt<2;++rt)
        #pragma unroll
        for (int i=0;i<4;++i){
            int r = rt*16 + lg*4 + i;
            float S = red[0][r][0]+red[1][r][0]+red[2][r][0]+red[3][r][0];
            float Q = red[0][r][1]+red[1][r][1]+red[2][r][1]+red[3][r][1];
            float mean = S * (1.f/256.f);
            float var  = Q * (1.f/256.f) - mean*mean;
            float rs = rsqrtf(var + LN_EPS);
            #pragma unroll
            for (int c=0;c<4;++c){
                int colg = w*64 + c*16 + l15;
                float v = (xv[rt][c][i]-mean)*rs*g1c[c] + t1c[c];
                A2s[r*NP + colg] = (short)f2bf(gelu_f(v));
            }
        }
    __syncthreads();

    // ---- phase 2: (32x256)@(256x128) ----
    f32x4 acc2[2][2];
    #pragma unroll
    for (int rt=0;rt<2;++rt)
        #pragma unroll
        for (int c=0;c<2;++c) acc2[rt][c] = (f32x4){0.f,0.f,0.f,0.f};

    #pragma unroll 2
    for (int kc = 0; kc < 8; ++kc){
        int k0 = kc*32 + lg*8;
        bf16x8 a0 = *(const bf16x8*)&A2s[(l15     )*NP + k0];
        bf16x8 a1 = *(const bf16x8*)&A2s[(l15 + 16)*NP + k0];
        #pragma unroll
        for (int c=0;c<2;++c){
            int colg = w*32 + c*16 + l15;
            bf16x8 b = *(const bf16x8*)&W2T[(size_t)colg*256 + k0];
            acc2[0][c] = __builtin_amdgcn_mfma_f32_16x16x32_bf16(a0, b, acc2[0][c], 0, 0, 0);
            acc2[1][c] = __builtin_amdgcn_mfma_f32_16x16x32_bf16(a1, b, acc2[1][c], 0, 0, 0);
        }
    }

    // ---- epilogue 2: +b2, LN(128), residual -> h + h_bf ----
    float b2c[2], g2c[2], t2c[2];
    #pragma unroll
    for (int c=0;c<2;++c){
        int colg = w*32 + c*16 + l15;
        b2c[c] = b2[colg]; g2c[c] = g2[colg]; t2c[c] = bt2[colg];
    }
    float yv[2][2][4];
    #pragma unroll
    for (int rt=0;rt<2;++rt)
        #pragma unroll
        for (int c=0;c<2;++c)
            #pragma unroll
            for (int i=0;i<4;++i) yv[rt][c][i] = acc2[rt][c][i] + b2c[c];

    __syncthreads();
    #pragma unroll
    for (int rt=0;rt<2;++rt)
        #pragma unroll
        for (int i=0;i<4;++i){
            float s=0.f, q=0.f;
            #pragma unroll
            for (int c=0;c<2;++c){ float v=yv[rt][c][i]; s+=v; q+=v*v; }
            #pragma unroll
            for (int m=1;m<16;m<<=1){ s += __shfl_xor(s,m); q += __shfl_xor(q,m); }
            if (l15 == 0){
                int r = rt*16 + lg*4 + i;
                red[w][r][0] = s;
                red[w][r][1] = q;
            }
        }
    __syncthreads();

    #pragma unroll
    for (int rt=0;rt<2;++rt)
        #pragma unroll
        for (int i=0;i<4;++i){
            int r = rt*16 + lg*4 + i;
            int gn = nBase + r;
            if (gn < NN){
                float S = red[0][r][0]+red[1][r][0]+red[2][r][0]+red[3][r][0];
                float Q = red[0][r][1]+red[1][r][1]+red[2][r][1]+red[3][r][1];
                float mean = S * (1.f/128.f);
                float var  = Q * (1.f/128.f) - mean*mean;
                float rs = rsqrtf(var + LN_EPS);
                size_t gbase = (size_t)gn*HD;
                #pragma unroll
                for (int c=0;c<2;++c){
                    int colg = w*32 + c*16 + l15;
                    float v = (yv[rt][c][i]-mean)*rs*g2c[c] + t2c[c];
                    float nv = h[gbase + colg] + v;
                    h[gbase + colg] = nv;
                    h_bf[gbase + colg] = f2bf(nv);
                }
            }
        }
}

// ---------------- decoder ----------------
__global__ __launch_bounds__(128) void k_decode(
    const float* __restrict__ h, const float* __restrict__ W1,
    const float* __restrict__ b1, const float* __restrict__ W2,
    const float* __restrict__ b2, float* __restrict__ out)
{
    int n = blockIdx.x, t = threadIdx.x;
    __shared__ float hs[128];
    __shared__ float red[8];
    hs[t] = h[(size_t)n*HD + t];
    __syncthreads();
    float o = b1[t];
    #pragma unroll 8
    for (int k = 0; k < 128; ++k) o += hs[k] * W1[k*128 + t];
    o = gelu_f(o);
    float p0 = o*W2[t*4+0], p1 = o*W2[t*4+1], p2 = o*W2[t*4+2], p3 = o*W2[t*4+3];
    #pragma unroll
    for (int m = 32; m >= 1; m >>= 1){
        p0 += __shfl_xor(p0, m); p1 += __shfl_xor(p1, m);
        p2 += __shfl_xor(p2, m); p3 += __shfl_xor(p3, m);
    }
    int wave = t >> 6;
    if ((t & 63) == 0){ red[wave*4+0]=p0; red[wave*4+1]=p1; red[wave*4+2]=p2; red[wave*4+3]=p3; }
    __syncthreads();
    if (t < 4) out[(size_t)n*4 + t] = red[t] + red[4+t] + b2[t];
}

// ---------------- launch ----------------
extern "C" void kernel_launch(void* const* d_in, const int* in_sizes, int n_in,
                              void* d_out, int out_size, void* d_ws, size_t ws_size,
                              hipStream_t stream)
{
    const float* x      = (const float*)d_in[0];
    const int*   eidx   = (const int*)d_in[1];
    const float* eattr  = (const float*)d_in[2];
    const float* enc_W  = (const float*)d_in[3];
    const float* enc_b  = (const float*)d_in[4];
    const float* enc_g  = (const float*)d_in[5];
    const float* enc_bt = (const float*)d_in[6];
    const float* ee_W   = (const float*)d_in[7];
    const float* ee_b   = (const float*)d_in[8];
    const float* eW1    = (const float*)d_in[9];
    const float* eb1    = (const float*)d_in[10];
    const float* eg1    = (const float*)d_in[11];
    const float* ebt1   = (const float*)d_in[12];
    const float* eW2    = (const float*)d_in[13];
    const float* eb2    = (const float*)d_in[14];
    const float* eg2    = (const float*)d_in[15];
    const float* ebt2   = (const float*)d_in[16];
    const float* nW1    = (const float*)d_in[17];
    const float* nb1    = (const float*)d_in[18];
    const float* ng1    = (const float*)d_in[19];
    const float* nbt1   = (const float*)d_in[20];
    const float* nW2    = (const float*)d_in[21];
    const float* nb2    = (const float*)d_in[22];
    const float* ng2    = (const float*)d_in[23];
    const float* nbt2   = (const float*)d_in[24];
    const float* dec_W1 = (const float*)d_in[25];
    const float* dec_b1 = (const float*)d_in[26];
    const float* dec_W2 = (const float*)d_in[27];
    const float* dec_b2 = (const float*)d_in[28];

    const int* row = eidx;
    const int* col = eidx + NE;

    char* ws0 = (char*)d_ws;
    char* ws = ws0;
    auto alloc = [&](size_t bytes) -> char* {
        char* p = ws;
        ws += (bytes + 255) & ~(size_t)255;
        return p;
    };
    ushort_t* ea      = (ushort_t*)alloc((size_t)NE*HD*2);       // 153.6 MB
    float*    h       = (float*)   alloc((size_t)NN*HD*4);       // 25.6 MB
    ushort_t* h_bf    = (ushort_t*)alloc((size_t)NN*HD*2);       // 12.8 MB
    ushort_t* W1Tb    = (ushort_t*)alloc((size_t)NL*256*384*2);  // 1.97 MB
    ushort_t* W2Tb    = (ushort_t*)alloc((size_t)NL*128*256*2);  // 0.66 MB
    ushort_t* nW1Tb   = (ushort_t*)alloc((size_t)NL*256*256*2);  // 1.31 MB
    ushort_t* nW2Tb   = (ushort_t*)alloc((size_t)NL*128*256*2);  // 0.66 MB
    int*      cnt     = (int*)     alloc((size_t)NN*4);
    int*      rowSt   = (int*)     alloc((size_t)NN*4);
    int*      fill    = (int*)     alloc((size_t)NN*4);
    float*    invcnt  = (float*)   alloc((size_t)NN*4);
    int*      edgeIds = (int*)     alloc((size_t)NE*4);
    int*      bsum    = (int*)     alloc(256*4);
    int*      boff    = (int*)     alloc(256*4);

    size_t need = (size_t)(ws - ws0);
    if (ws_size < need){
        k_sentinel_out<<<(out_size+255)/256, 256, 0, stream>>>((float*)d_out, out_size, 3.0f);
        return;
    }

    hipMemsetAsync(cnt,  0, (size_t)NN*4, stream);
    hipMemsetAsync(fill, 0, (size_t)NN*4, stream);

    k_wt<<<(NL*384*256+255)/256, 256, 0, stream>>>(eW1, W1Tb, 384, 256);
    k_wt<<<(NL*256*128+255)/256, 256, 0, stream>>>(eW2, W2Tb, 256, 128);
    k_wt<<<(NL*256*256+255)/256, 256, 0, stream>>>(nW1, nW1Tb, 256, 256);
    k_wt<<<(NL*256*128+255)/256, 256, 0, stream>>>(nW2, nW2Tb, 256, 128);

    k_encode_nodes<<<NN, 128, 0, stream>>>(x, enc_W, enc_b, enc_g, enc_bt, h, h_bf);
    k_encode_edges<<<NE/2, 256, 0, stream>>>(eattr, ee_W, ee_b, ea);

    k_hist <<<(NE+255)/256, 256, 0, stream>>>(col, cnt);
    k_scan1<<<NBLK, 256, 0, stream>>>(cnt, bsum);
    k_scan2<<<1, 256, 0, stream>>>(bsum, boff);
    k_scan3<<<NBLK, 256, 0, stream>>>(cnt, boff, rowSt, invcnt);
    k_fill <<<(NE+255)/256, 256, 0, stream>>>(col, rowSt, fill, edgeIds);

    for (int l = 0; l < NL; ++l){
        k_edge_update<<<NE/EB, 256, 0, stream>>>(h_bf, ea, row, col,
            W1Tb + (size_t)l*256*384, eb1 + l*256, eg1 + l*256, ebt1 + l*256,
            W2Tb + (size_t)l*128*256, eb2 + l*128, eg2 + l*128, ebt2 + l*128);
        k_node_update<<<(NN+31)/32, 256, 0, stream>>>(h, h_bf, ea, rowSt, cnt, invcnt, edgeIds,
            nW1Tb + (size_t)l*256*256, nb1 + l*256, ng1 + l*256, nbt1 + l*256,
            nW2Tb + (size_t)l*128*256, nb2 + l*128, ng2 + l*128, nbt2 + l*128);
    }

    k_decode<<<NN, 128, 0, stream>>>(h, dec_W1, dec_b1, dec_W2, dec_b2, (float*)d_out);
}